// Round 3
// baseline (27161.951 us; speedup 1.0000x reference)
//
#include <hip/hip_runtime.h>
#include <hip/hip_bf16.h>

#define HW 4096
#define WD 64
#define HT 64
#define NEGV -1000000000.0f

typedef const void* vp;

__device__ __forceinline__ float b2f(__hip_bfloat16 v){ return __bfloat162float(v); }
// dtype-dispatched input load: f=1 -> fp32, f=0 -> bf16
__device__ __forceinline__ float ldf(vp p, size_t i, int f){
  return f ? ((const float*)p)[i] : b2f(((const __hip_bfloat16*)p)[i]);
}

// ---------- dtype detector: fp32 data read as u16 has uniform-random low half-words ----------
__global__ void k_detect(int* flag, const unsigned short* p){
  __shared__ int cnt;
  if(threadIdx.x==0) cnt=0;
  __syncthreads();
  int c=0;
  for(int i=threadIdx.x; i<512; i+=256){
    int e = (p[i]>>7)&0xFF;
    if(e>150 || e<100) c++;
  }
  atomicAdd(&cnt, c);
  __syncthreads();
  if(threadIdx.x==0) *flag = (cnt>32) ? 1 : 0;  // 1 = fp32 inputs
}

// ---------- elementwise ----------
__global__ void k_cvt(float* dst, vp src, int n, const int* dflag){
  int f = *dflag;
  int i = blockIdx.x*256 + threadIdx.x;
  if(i<n) dst[i] = ldf(src, i, f);
}

__global__ void k_addpos(float* xi, const float* memf, vp pos, int n, const int* dflag){
  int f = *dflag;
  int i = blockIdx.x*256 + threadIdx.x;
  if(i<n) xi[i] = memf[i] + ldf(pos, i, f);
}

__global__ void k_zero(float* p, int n){
  int i = blockIdx.x*256 + threadIdx.x;
  if(i<n) p[i] = 0.f;
}

// memory_2d writer at element offset 102400 of d_out, dtype per flag
__global__ void k_write_mem(void* out, const float* src, int n, const int* dflag){
  int f = *dflag;
  int i = blockIdx.x*256 + threadIdx.x;
  if(i<n){
    if(f) ((float*)out)[102400 + i] = src[i];
    else  ((__hip_bfloat16*)out)[102400 + i] = __float2bfloat16(src[i]);
  }
}

// ---------- 3x3 conv, SAME pad, no bias; optional relu; optional channel-concat input ----------
// grid (HT, Cout/4, B), block 64 (w). Each thread: 4 output channels.
__global__ __launch_bounds__(64) void k_conv3x3(
    float* __restrict__ out, const float* __restrict__ in1, const float* __restrict__ in2,
    vp w, size_t wo, int Cin1, int Cin2, int Cout, int relu, const int* dflag)
{
  __shared__ float wl[4][64][9];
  const int f = *dflag;
  const int tid = threadIdx.x;
  const int h = blockIdx.x;
  const int co0 = blockIdx.y*4;
  const int b = blockIdx.z;
  const int Cin = Cin1 + Cin2;
  float acc0=0.f, acc1=0.f, acc2=0.f, acc3=0.f;
  for(int c0=0; c0<Cin; c0+=64){
    for(int idx=tid; idx<4*64*9; idx+=64){
      int oc = idx/576; int rem = idx - oc*576; int ci = rem/9; int t = rem - ci*9;
      wl[oc][ci][t] = ldf(w, wo + ((size_t)(co0+oc)*Cin + c0+ci)*9 + t, f);
    }
    __syncthreads();
    for(int ci=0; ci<64; ci++){
      int cg = c0 + ci;
      const float* src = (cg < Cin1) ? (in1 + ((size_t)(b*Cin1+cg))*HW)
                                     : (in2 + ((size_t)(b*Cin2+(cg-Cin1)))*HW);
      #pragma unroll
      for(int kh=0; kh<3; kh++){
        int r = h + kh - 1;
        if(r < 0 || r >= HT) continue;
        const float* row = src + r*WD;
        float xm = (tid>0)  ? row[tid-1] : 0.f;
        float x0 = row[tid];
        float xp = (tid<63) ? row[tid+1] : 0.f;
        acc0 += xm*wl[0][ci][kh*3+0] + x0*wl[0][ci][kh*3+1] + xp*wl[0][ci][kh*3+2];
        acc1 += xm*wl[1][ci][kh*3+0] + x0*wl[1][ci][kh*3+1] + xp*wl[1][ci][kh*3+2];
        acc2 += xm*wl[2][ci][kh*3+0] + x0*wl[2][ci][kh*3+1] + xp*wl[2][ci][kh*3+2];
        acc3 += xm*wl[3][ci][kh*3+0] + x0*wl[3][ci][kh*3+1] + xp*wl[3][ci][kh*3+2];
      }
    }
    __syncthreads();
  }
  if(relu){
    acc0 = fmaxf(acc0,0.f); acc1 = fmaxf(acc1,0.f);
    acc2 = fmaxf(acc2,0.f); acc3 = fmaxf(acc3,0.f);
  }
  size_t ob = ((size_t)(b*Cout)+co0)*HW + h*WD + tid;
  out[ob]        = acc0;
  out[ob+HW]     = acc1;
  out[ob+2*HW]   = acc2;
  out[ob+3*HW]   = acc3;
}

// ---------- 1x1 conv with bias (Cin<=64) ----------
// grid (HW/64, Cout, B), block 64
__global__ __launch_bounds__(64) void k_conv1x1(
    float* __restrict__ out, const float* __restrict__ in, vp w, size_t wo,
    vp bias, size_t bo, int Cin, int Cout, const int* dflag)
{
  __shared__ float wl[64];
  int f = *dflag;
  int tid = threadIdx.x; int co = blockIdx.y; int b = blockIdx.z;
  int p = blockIdx.x*64 + tid;
  for(int i=tid; i<Cin; i+=64) wl[i] = ldf(w, wo + (size_t)co*Cin + i, f);
  __syncthreads();
  float acc = ldf(bias, bo + co, f);
  for(int c=0; c<Cin; c++) acc += in[((size_t)(b*Cin+c))*HW + p]*wl[c];
  out[((size_t)(b*Cout+co))*HW + p] = acc;
}

// ---------- criss-cross energies + softmax ----------
// grid (WD, HT, B), block 128.
__global__ __launch_bounds__(128) void k_cc_att(
    float* __restrict__ att, const float* __restrict__ q, const float* __restrict__ k)
{
  __shared__ float qv[8];
  __shared__ float ev[128];
  int j = threadIdx.x; int w = blockIdx.x; int h = blockIdx.y; int b = blockIdx.z;
  if(j < 8) qv[j] = q[((size_t)(b*8+j))*HW + h*WD + w];
  __syncthreads();
  float e = 0.f;
  if(j < 64){
    #pragma unroll
    for(int c=0;c<8;c++) e += qv[c]*k[((size_t)(b*8+c))*HW + j*WD + w];
    if(j == h) e += NEGV;
  } else {
    int jj = j - 64;
    #pragma unroll
    for(int c=0;c<8;c++) e += qv[c]*k[((size_t)(b*8+c))*HW + h*WD + jj];
  }
  ev[j] = e;
  __syncthreads();
  for(int s=64; s>0; s>>=1){ if(j<s) ev[j] = fmaxf(ev[j], ev[j+s]); __syncthreads(); }
  float m = ev[0];
  __syncthreads();
  float p = __expf(e - m);
  ev[j] = p;
  __syncthreads();
  for(int s=64; s>0; s>>=1){ if(j<s) ev[j] += ev[j+s]; __syncthreads(); }
  float inv = 1.0f/ev[0];
  att[(((size_t)(b*HT+h))*WD + w)*128 + j] = p*inv;
}

// ---------- criss-cross aggregation: out = gamma*(outH+outW) + x ----------
// grid (HT, WD, B), block 64 (c)
__global__ __launch_bounds__(64) void k_cc_agg(
    float* __restrict__ out, const float* __restrict__ v, const float* __restrict__ att,
    const float* __restrict__ x, vp gamma, size_t go, const int* dflag)
{
  __shared__ float al[128];
  int f = *dflag;
  int c = threadIdx.x; int h = blockIdx.x; int w = blockIdx.y; int b = blockIdx.z;
  const float* ar = att + (((size_t)(b*HT+h))*WD + w)*128;
  al[c] = ar[c]; al[c+64] = ar[c+64];
  __syncthreads();
  float g = ldf(gamma, go, f);
  const float* vb = v + ((size_t)(b*64+c))*HW;
  float acc = 0.f;
  #pragma unroll 4
  for(int j=0;j<64;j++) acc += vb[(size_t)j*WD + w]*al[j];
  const float* vr = vb + (size_t)h*WD;
  #pragma unroll 4
  for(int j=0;j<64;j++) acc += vr[j]*al[64+j];
  size_t idx = ((size_t)(b*64+c))*HW + (size_t)h*WD + w;
  out[idx] = g*acc + x[idx];
}

// ---------- token transpose for decoder memory: mem_t[b,s,c] ----------
__global__ void k_mk_tokens(float* __restrict__ mem_t, const float* __restrict__ memf)
{
  int c = threadIdx.x; int s = blockIdx.x; int b = blockIdx.y;
  mem_t[((size_t)(b*HW+s))*256 + c] = memf[((size_t)(b*256+c))*HW + s];
}

// ---------- GEMM: Y[M,N] = act(X[M,K] @ W[N,K]^T + bias) ----------
// grid (N/64, ceil(M/64)), block 256; 64x64 tile, BK=16, 4x4 per thread.
// pos2 != null (cross-attn K proj, gm=b*4096+s): X_eff[gm][k] += pos2_NCHW[b,k,s]
__global__ __launch_bounds__(256) void k_gemm(
    float* __restrict__ Y, const float* __restrict__ X, vp W, size_t wo,
    vp bias, size_t bo, vp pos2, int M, int N, int K, int relu, const int* dflag)
{
  __shared__ float Xs[16][68];
  __shared__ float Ws[16][68];
  int f = *dflag;
  int tid = threadIdx.x;
  int bn = blockIdx.x*64, bm = blockIdx.y*64;
  int tx = tid & 15, ty = tid >> 4;
  int mload = tid >> 2;
  int k4 = (tid & 3) * 4;
  float acc[4][4] = {{0}};
  for(int k0=0; k0<K; k0+=16){
    float4 xv = make_float4(0.f,0.f,0.f,0.f);
    int gm = bm + mload;
    if(gm < M){
      xv = *(const float4*)(X + (size_t)gm*K + k0 + k4);
      if(pos2){
        int b = gm >> 12, s = gm & 4095;
        size_t pb = ((size_t)(b*256 + k0 + k4))*HW + s;
        xv.x += ldf(pos2, pb,      f);
        xv.y += ldf(pos2, pb+HW,   f);
        xv.z += ldf(pos2, pb+2*HW, f);
        xv.w += ldf(pos2, pb+3*HW, f);
      }
    }
    Xs[k4+0][mload] = xv.x; Xs[k4+1][mload] = xv.y;
    Xs[k4+2][mload] = xv.z; Xs[k4+3][mload] = xv.w;
    size_t wr = wo + (size_t)(bn + mload)*K + k0 + k4;
    Ws[k4+0][mload] = ldf(W, wr,   f); Ws[k4+1][mload] = ldf(W, wr+1, f);
    Ws[k4+2][mload] = ldf(W, wr+2, f); Ws[k4+3][mload] = ldf(W, wr+3, f);
    __syncthreads();
    #pragma unroll
    for(int kk=0; kk<16; kk++){
      float a0=Xs[kk][ty*4+0], a1=Xs[kk][ty*4+1], a2=Xs[kk][ty*4+2], a3=Xs[kk][ty*4+3];
      float b0=Ws[kk][tx*4+0], b1=Ws[kk][tx*4+1], b2=Ws[kk][tx*4+2], b3=Ws[kk][tx*4+3];
      acc[0][0]+=a0*b0; acc[0][1]+=a0*b1; acc[0][2]+=a0*b2; acc[0][3]+=a0*b3;
      acc[1][0]+=a1*b0; acc[1][1]+=a1*b1; acc[1][2]+=a1*b2; acc[1][3]+=a1*b3;
      acc[2][0]+=a2*b0; acc[2][1]+=a2*b1; acc[2][2]+=a2*b2; acc[2][3]+=a2*b3;
      acc[3][0]+=a3*b0; acc[3][1]+=a3*b1; acc[3][2]+=a3*b2; acc[3][3]+=a3*b3;
    }
    __syncthreads();
  }
  #pragma unroll
  for(int i=0;i<4;i++){
    int m = bm + ty*4 + i;
    if(m >= M) continue;
    #pragma unroll
    for(int j=0;j<4;j++){
      int n = bn + tx*4 + j;
      float vv = acc[i][j] + (bias ? ldf(bias, bo + n, f) : 0.f);
      if(relu) vv = fmaxf(vv, 0.f);
      Y[(size_t)m*N + n] = vv;
    }
  }
}

// ---------- fused attention (one wave per (b,h,l)), online softmax ----------
__global__ __launch_bounds__(64) void k_attn(
    float* __restrict__ out, const float* __restrict__ q,
    const float* __restrict__ k, const float* __restrict__ v,
    int B, int S, size_t bstride, size_t sstride, float scale)
{
  int lane = threadIdx.x;
  int l = blockIdx.x, h = blockIdx.y, b = blockIdx.z;
  const float4* qp = (const float4*)(q + ((size_t)(l*B+b))*256 + h*32);
  float4 qr[8];
  #pragma unroll
  for(int d=0; d<8; d++) qr[d] = qp[d];
  float m = -1e30f, lsum = 0.f;
  float acc[32];
  #pragma unroll
  for(int d=0; d<32; d++) acc[d] = 0.f;
  for(int s=lane; s<S; s+=64){
    const float4* kp = (const float4*)(k + b*bstride + (size_t)s*sstride + h*32);
    const float4* vp2 = (const float4*)(v + b*bstride + (size_t)s*sstride + h*32);
    float e = 0.f;
    #pragma unroll
    for(int d=0; d<8; d++){
      float4 kv = kp[d];
      e += qr[d].x*kv.x + qr[d].y*kv.y + qr[d].z*kv.z + qr[d].w*kv.w;
    }
    e *= scale;
    float nm = fmaxf(m, e);
    float ff = __expf(m - nm);
    float p = __expf(e - nm);
    lsum = lsum*ff + p;
    #pragma unroll
    for(int d=0; d<8; d++){
      float4 vv = vp2[d];
      acc[4*d+0] = acc[4*d+0]*ff + p*vv.x;
      acc[4*d+1] = acc[4*d+1]*ff + p*vv.y;
      acc[4*d+2] = acc[4*d+2]*ff + p*vv.z;
      acc[4*d+3] = acc[4*d+3]*ff + p*vv.w;
    }
    m = nm;
  }
  #pragma unroll
  for(int off=32; off>0; off>>=1){
    float om = __shfl_xor(m, off);
    float ol = __shfl_xor(lsum, off);
    float nm = fmaxf(m, om);
    float fa = __expf(m - nm), fb = __expf(om - nm);
    lsum = lsum*fa + ol*fb;
    #pragma unroll
    for(int d=0; d<32; d++){
      float oa = __shfl_xor(acc[d], off);
      acc[d] = acc[d]*fa + oa*fb;
    }
    m = nm;
  }
  if(lane == 0){
    float inv = 1.0f/lsum;
    float* op = out + ((size_t)(l*B+b))*256 + h*32;
    #pragma unroll
    for(int d=0; d<32; d++) op[d] = acc[d]*inv;
  }
}

// ---------- LayerNorm over C=256 ----------
__global__ __launch_bounds__(256) void k_ln(
    float* dst, const float* x, const float* t2, vp g, vp bb, size_t go, const int* dflag)
{
  __shared__ float red[256];
  int f = *dflag;
  int c = threadIdx.x; int tok = blockIdx.x;
  float v = x[(size_t)tok*256 + c];
  if(t2) v += t2[(size_t)tok*256 + c];
  red[c] = v; __syncthreads();
  for(int s=128; s>0; s>>=1){ if(c<s) red[c] += red[c+s]; __syncthreads(); }
  float mu = red[0]*(1.f/256.f);
  __syncthreads();
  float dv = v - mu;
  red[c] = dv*dv; __syncthreads();
  for(int s=128; s>0; s>>=1){ if(c<s) red[c] += red[c+s]; __syncthreads(); }
  float var = red[0]*(1.f/256.f);
  float r = rsqrtf(var + 1e-5f);
  dst[(size_t)tok*256 + c] = dv*r*ldf(g, go+c, f) + ldf(bb, go+c, f);
}

// ---------- xq = outq + qe (broadcast over batch) ----------
__global__ void k_addqe(float* dst, const float* outq, vp qe, const int* dflag){
  int f = *dflag;
  int c = threadIdx.x; int tok = blockIdx.x; int l = tok >> 2;
  dst[(size_t)tok*256 + c] = outq[(size_t)tok*256 + c] + ldf(qe, (size_t)l*256 + c, f);
}

// ---------- hs writer: hs[0,b,l,c] = lnout[(l*4+b), c] ----------
__global__ void k_write_hs(void* out, const float* lnout, const int* dflag){
  int f = *dflag;
  int c = threadIdx.x; int tok = blockIdx.x; int l = tok >> 2; int b = tok & 3;
  float v = lnout[(size_t)tok*256 + c];
  size_t o = ((size_t)(b*100+l))*256 + c;
  if(f) ((float*)out)[o] = v;
  else  ((__hip_bfloat16*)out)[o] = __float2bfloat16(v);
}

extern "C" void kernel_launch(void* const* d_in, const int* in_sizes, int n_in,
                              void* d_out, int out_size, void* d_ws, size_t ws_size,
                              hipStream_t stream) {
  vp src       = d_in[0];
  // d_in[1] = mask (all false) — unused
  vp query_emb = d_in[2];
  vp pos       = d_in[3];
  vp conva_w   = d_in[4];
  vp q_w = d_in[5];  vp q_b = d_in[6];
  vp k_w = d_in[7];  vp k_b = d_in[8];
  vp v_w = d_in[9];  vp v_b = d_in[10];
  vp gamma = d_in[11];
  vp convb_w = d_in[12];
  vp bneck_w = d_in[13];
  vp sa_in_w = d_in[14];  vp sa_in_b = d_in[15];
  vp sa_out_w = d_in[16]; vp sa_out_b = d_in[17];
  vp ca_in_w = d_in[18];  vp ca_in_b = d_in[19];
  vp ca_out_w = d_in[20]; vp ca_out_b = d_in[21];
  vp lin1_w = d_in[22];   vp lin1_b = d_in[23];
  vp lin2_w = d_in[24];   vp lin2_b = d_in[25];
  vp n1g = d_in[26]; vp n1b = d_in[27];
  vp n2g = d_in[28]; vp n2b = d_in[29];
  vp n3g = d_in[30]; vp n3b = d_in[31];
  vp normg = d_in[32]; vp normb = d_in[33];

  // ---- compact workspace layout (15,532,032 floats + flag = 59.3 MB) ----
  const size_t MEG = 1048576;
  float* ws   = (float*)d_ws;
  float* memf  = ws;                    // 4M floats
  float* xi    = ws + 4*MEG;            // 4M
  float* y64a  = ws + 8*MEG;            // 1M
  float* y64b  = ws + 9*MEG;            // 1M
  float* vb_   = ws + 10*MEG;           // 1M
  float* qb_   = ws + 11*MEG;           // 128K
  float* kb_   = ws + 11*MEG + 131072;  // 128K
  float* attb  = ws + 11*MEG + 262144;  // 2M (ends 13.25M)
  float* y256  = ws + 9*MEG;            // 4M (overlaps dead cc buffers)
  float* mem_t = xi;                    // decoder
  float* kproj = memf;                  // decoder (memf dead after output write)
  float* vproj = ws + 8*MEG;            // decoder
  float* sm    = ws + 13*MEG + 262144;
  float* outq   = sm;
  float* xq     = sm + 102400;
  float* qproj  = sm + 204800;
  float* kself  = sm + 307200;
  float* vself  = sm + 409600;
  float* attout = sm + 512000;
  float* t2     = sm + 614400;
  float* ffn1   = sm + 716800;          // 819200
  float* lnout  = sm + 1536000;         // ends 1,638,400
  int*   dflag  = (int*)(ws + 15532032);

  const int NFULL = 4194304;
  const float scale = 0.17677669529663687f; // 32^-0.5

  k_detect<<<1, 256, 0, stream>>>(dflag, (const unsigned short*)src);
  k_cvt<<<(NFULL+255)/256, 256, 0, stream>>>(memf, src, NFULL, dflag);

  // ------------- encoder -------------
  for(int i=0; i<6; i++){
    k_addpos<<<(NFULL+255)/256, 256, 0, stream>>>(xi, memf, pos, NFULL, dflag);
    k_conv3x3<<<dim3(64,16,4), 64, 0, stream>>>(y64a, xi, nullptr,
        conva_w, (size_t)i*147456, 256, 0, 64, 1, dflag);
    for(int pass=0; pass<2; pass++){
      const float* cx = pass ? y64b : y64a;
      float* cy       = pass ? y64a : y64b;
      k_conv1x1<<<dim3(64,8,4),  64, 0, stream>>>(qb_, cx, q_w, (size_t)i*512,  q_b, (size_t)i*8,  64, 8,  dflag);
      k_conv1x1<<<dim3(64,8,4),  64, 0, stream>>>(kb_, cx, k_w, (size_t)i*512,  k_b, (size_t)i*8,  64, 8,  dflag);
      k_conv1x1<<<dim3(64,64,4), 64, 0, stream>>>(vb_, cx, v_w, (size_t)i*4096, v_b, (size_t)i*64, 64, 64, dflag);
      k_cc_att<<<dim3(64,64,4), 128, 0, stream>>>(attb, qb_, kb_);
      k_cc_agg<<<dim3(64,64,4), 64, 0, stream>>>(cy, vb_, attb, cx, gamma, (size_t)i, dflag);
    }
    k_conv3x3<<<dim3(64,64,4), 64, 0, stream>>>(y256, y64a, nullptr,
        convb_w, (size_t)i*147456, 64, 0, 256, 1, dflag);
    k_conv3x3<<<dim3(64,64,4), 64, 0, stream>>>(memf, xi, y256,
        bneck_w, (size_t)i*1179648, 256, 256, 256, 0, dflag);
  }

  // ------------- decoder prep (before kproj overwrites memf) -------------
  k_mk_tokens<<<dim3(4096,4), 256, 0, stream>>>(mem_t, memf);
  k_write_mem<<<(NFULL+255)/256, 256, 0, stream>>>(d_out, memf, NFULL, dflag);
  k_zero<<<400, 256, 0, stream>>>(outq, 102400);

  // ------------- decoder layers -------------
  for(int i=0; i<6; i++){
    size_t iw = (size_t)i*196608, ib = (size_t)i*768;
    size_t ow = (size_t)i*65536,  ob = (size_t)i*256;
    // self-attention
    k_addqe<<<400, 256, 0, stream>>>(xq, outq, query_emb, dflag);
    k_gemm<<<dim3(4,7), 256, 0, stream>>>(qproj, xq,   sa_in_w, iw,        sa_in_b, ib,     nullptr, 400, 256, 256, 0, dflag);
    k_gemm<<<dim3(4,7), 256, 0, stream>>>(kself, xq,   sa_in_w, iw+65536,  sa_in_b, ib+256, nullptr, 400, 256, 256, 0, dflag);
    k_gemm<<<dim3(4,7), 256, 0, stream>>>(vself, outq, sa_in_w, iw+131072, sa_in_b, ib+512, nullptr, 400, 256, 256, 0, dflag);
    k_attn<<<dim3(100,8,4), 64, 0, stream>>>(attout, qproj, kself, vself,
        4, 100, (size_t)256, (size_t)1024, scale);
    k_gemm<<<dim3(4,7), 256, 0, stream>>>(t2, attout, sa_out_w, ow, sa_out_b, ob, nullptr, 400, 256, 256, 0, dflag);
    k_ln<<<400, 256, 0, stream>>>(outq, outq, t2, n1g, n1b, ob, dflag);
    // cross-attention (K proj fuses +pos)
    k_addqe<<<400, 256, 0, stream>>>(xq, outq, query_emb, dflag);
    k_gemm<<<dim3(4,7),   256, 0, stream>>>(qproj, xq,    ca_in_w, iw,        ca_in_b, ib,     nullptr, 400,   256, 256, 0, dflag);
    k_gemm<<<dim3(4,256), 256, 0, stream>>>(kproj, mem_t, ca_in_w, iw+65536,  ca_in_b, ib+256, pos,     16384, 256, 256, 0, dflag);
    k_gemm<<<dim3(4,256), 256, 0, stream>>>(vproj, mem_t, ca_in_w, iw+131072, ca_in_b, ib+512, nullptr, 16384, 256, 256, 0, dflag);
    k_attn<<<dim3(100,8,4), 64, 0, stream>>>(attout, qproj, kproj, vproj,
        4, 4096, (size_t)1048576, (size_t)256, scale);
    k_gemm<<<dim3(4,7), 256, 0, stream>>>(t2, attout, ca_out_w, ow, ca_out_b, ob, nullptr, 400, 256, 256, 0, dflag);
    k_ln<<<400, 256, 0, stream>>>(outq, outq, t2, n2g, n2b, ob, dflag);
    // FFN
    k_gemm<<<dim3(32,7), 256, 0, stream>>>(ffn1, outq, lin1_w, (size_t)i*524288, lin1_b, (size_t)i*2048, nullptr, 400, 2048, 256, 1, dflag);
    k_gemm<<<dim3(4,7),  256, 0, stream>>>(t2,   ffn1, lin2_w, (size_t)i*524288, lin2_b, ob,             nullptr, 400, 256, 2048, 0, dflag);
    k_ln<<<400, 256, 0, stream>>>(outq, outq, t2, n3g, n3b, ob, dflag);
  }

  // final norm + hs output
  k_ln<<<400, 256, 0, stream>>>(lnout, outq, nullptr, normg, normb, (size_t)0, dflag);
  k_write_hs<<<400, 256, 0, stream>>>(d_out, lnout, dflag);
}

// Round 4
// 16771.178 us; speedup vs baseline: 1.6196x; 1.6196x over previous
//
#include <hip/hip_runtime.h>
#include <hip/hip_bf16.h>

#define HW 4096
#define WD 64
#define HT 64
#define NEGV -1000000000.0f

typedef const void* vp;
typedef __attribute__((ext_vector_type(8))) short bf16x8;
typedef __attribute__((ext_vector_type(4))) float f32x4;

__device__ __forceinline__ float b2f(__hip_bfloat16 v){ return __bfloat162float(v); }
// dtype-dispatched input load: f=1 -> fp32, f=0 -> bf16
__device__ __forceinline__ float ldf(vp p, size_t i, int f){
  return f ? ((const float*)p)[i] : b2f(((const __hip_bfloat16*)p)[i]);
}
__device__ __forceinline__ unsigned short f2b(float x){
  __hip_bfloat16 h = __float2bfloat16(x);
  return *reinterpret_cast<unsigned short*>(&h);
}

// ---------- dtype detector: fp32 data read as u16 has uniform-random low half-words ----------
__global__ void k_detect(int* flag, const unsigned short* p){
  __shared__ int cnt;
  if(threadIdx.x==0) cnt=0;
  __syncthreads();
  int c=0;
  for(int i=threadIdx.x; i<512; i+=256){
    int e = (p[i]>>7)&0xFF;
    if(e>150 || e<100) c++;
  }
  atomicAdd(&cnt, c);
  __syncthreads();
  if(threadIdx.x==0) *flag = (cnt>32) ? 1 : 0;  // 1 = fp32 inputs
}

// ---------- elementwise ----------
__global__ void k_cvt(float* dst, vp src, int n, const int* dflag){
  int f = *dflag;
  int i = blockIdx.x*256 + threadIdx.x;
  if(i<n) dst[i] = ldf(src, i, f);
}

__global__ void k_addpos(float* xi, const float* memf, vp pos, int n, const int* dflag){
  int f = *dflag;
  int i = blockIdx.x*256 + threadIdx.x;
  if(i<n) xi[i] = memf[i] + ldf(pos, i, f);
}

__global__ void k_zero(float* p, int n){
  int i = blockIdx.x*256 + threadIdx.x;
  if(i<n) p[i] = 0.f;
}

// memory_2d writer at element offset 102400 of d_out, dtype per flag
__global__ void k_write_mem(void* out, const float* src, int n, const int* dflag){
  int f = *dflag;
  int i = blockIdx.x*256 + threadIdx.x;
  if(i<n){
    if(f) ((float*)out)[102400 + i] = src[i];
    else  ((__hip_bfloat16*)out)[102400 + i] = __float2bfloat16(src[i]);
  }
}

// ---------- 3x3 conv via MFMA implicit GEMM ----------
// grid (HT, Cout/64, B), block 256 (4 waves). Each block: output tile (b, h, 64 co, 64 w).
// Wave wv covers co strip [co0+wv*16, +16) x all 64 w = 4 MFMA accumulators.
// K-loop: ci chunks of 32, 9 taps. fp32 accumulate, bf16 operands.
__global__ __launch_bounds__(256) void k_conv3x3_mfma(
    float* __restrict__ out, const float* __restrict__ in1, const float* __restrict__ in2,
    vp w, size_t wo, int Cin1, int Cin2, int Cout, int relu, const int* dflag)
{
  // padded rows of 40 ushorts: offsets stay 16B aligned (40%8==0), banks spread
  __shared__ __attribute__((aligned(16))) unsigned short Wl[9*64*40];  // [tap][co][ci]
  __shared__ __attribute__((aligned(16))) unsigned short Xs[3*66*40];  // [kh][w+1][ci]
  const int f = *dflag;
  const int tid  = threadIdx.x;
  const int lane = tid & 63;
  const int wv   = tid >> 6;
  const int quad = lane >> 4;
  const int l16  = lane & 15;
  const int h    = blockIdx.x;
  const int co0  = blockIdx.y*64;
  const int b    = blockIdx.z;
  const int Cin  = Cin1 + Cin2;

  // zero the w-pad columns (stay zero for whole kernel)
  if(tid < 96){
    int kh = tid>>5, ci = tid&31;
    Xs[(kh*66 + 0)*40 + ci]  = 0;
    Xs[(kh*66 + 65)*40 + ci] = 0;
  }

  f32x4 acc[4];
  #pragma unroll
  for(int nt=0; nt<4; nt++) acc[nt] = (f32x4){0.f,0.f,0.f,0.f};

  const int co_w = tid >> 2;       // weight-staging: this thread's co
  const int pgrp = tid & 3;        // ci groups of 8
  const int arow = (wv*16 + l16)*40 + quad*8;

  for(int c0=0; c0<Cin; c0+=32){
    __syncthreads();
    // ---- stage weights: Wl[tap][co][ci] = W[co0+co][c0+ci][tap] ----
    {
      const size_t wbase = wo + ((size_t)(co0+co_w)*Cin + c0 + pgrp*8)*9;
      #pragma unroll
      for(int ciL=0; ciL<8; ciL++){
        #pragma unroll
        for(int tap=0; tap<9; tap++){
          float wvv = ldf(w, wbase + ciL*9 + tap, f);
          Wl[(tap*64 + co_w)*40 + (pgrp*8 + ciL)] = f2b(wvv);
        }
      }
    }
    // ---- stage input rows h-1..h+1 for this ci chunk: Xs[kh][w+1][ci] ----
    #pragma unroll
    for(int it=0; it<6; it++){
      int t   = it*256 + tid;       // 0..1535
      int kh  = t >> 9;
      int rem = t & 511;
      int ci  = rem >> 4;
      int w4  = (rem & 15) << 2;
      int r   = h + kh - 1;
      float4 xv = make_float4(0.f,0.f,0.f,0.f);
      int cg = c0 + ci;
      if(r >= 0 && r < HT){
        const float* srcp = (cg < Cin1) ? in1 + ((size_t)(b*Cin1+cg))*HW
                                        : in2 + ((size_t)(b*Cin2+(cg-Cin1)))*HW;
        xv = *(const float4*)(srcp + r*WD + w4);
      }
      int base = (kh*66 + w4 + 1)*40 + ci;
      Xs[base]      = f2b(xv.x);
      Xs[base+40]   = f2b(xv.y);
      Xs[base+80]   = f2b(xv.z);
      Xs[base+120]  = f2b(xv.w);
    }
    __syncthreads();
    // ---- MFMA over 9 taps ----
    #pragma unroll
    for(int tap=0; tap<9; tap++){
      const int kh = tap/3, kw = tap%3;
      bf16x8 af = *(const bf16x8*)&Wl[tap*2560 + arow];
      #pragma unroll
      for(int nt=0; nt<4; nt++){
        bf16x8 bfr = *(const bf16x8*)&Xs[(kh*66 + nt*16 + l16 + kw)*40 + quad*8];
        acc[nt] = __builtin_amdgcn_mfma_f32_16x16x32_bf16(af, bfr, acc[nt], 0, 0, 0);
      }
    }
  }
  // ---- epilogue: D row = quad*4+r (co), col = l16 (w) ----
  #pragma unroll
  for(int nt=0; nt<4; nt++){
    #pragma unroll
    for(int r=0; r<4; r++){
      float vv = acc[nt][r];
      if(relu) vv = fmaxf(vv, 0.f);
      out[((size_t)(b*Cout + co0 + wv*16 + quad*4 + r))*HW + h*WD + nt*16 + l16] = vv;
    }
  }
}

// ---------- 1x1 conv with bias (Cin<=64) ----------
// grid (HW/64, Cout, B), block 64
__global__ __launch_bounds__(64) void k_conv1x1(
    float* __restrict__ out, const float* __restrict__ in, vp w, size_t wo,
    vp bias, size_t bo, int Cin, int Cout, const int* dflag)
{
  __shared__ float wl[64];
  int f = *dflag;
  int tid = threadIdx.x; int co = blockIdx.y; int b = blockIdx.z;
  int p = blockIdx.x*64 + tid;
  for(int i=tid; i<Cin; i+=64) wl[i] = ldf(w, wo + (size_t)co*Cin + i, f);
  __syncthreads();
  float acc = ldf(bias, bo + co, f);
  for(int c=0; c<Cin; c++) acc += in[((size_t)(b*Cin+c))*HW + p]*wl[c];
  out[((size_t)(b*Cout+co))*HW + p] = acc;
}

// ---------- criss-cross energies + softmax ----------
// grid (WD, HT, B), block 128.
__global__ __launch_bounds__(128) void k_cc_att(
    float* __restrict__ att, const float* __restrict__ q, const float* __restrict__ k)
{
  __shared__ float qv[8];
  __shared__ float ev[128];
  int j = threadIdx.x; int w = blockIdx.x; int h = blockIdx.y; int b = blockIdx.z;
  if(j < 8) qv[j] = q[((size_t)(b*8+j))*HW + h*WD + w];
  __syncthreads();
  float e = 0.f;
  if(j < 64){
    #pragma unroll
    for(int c=0;c<8;c++) e += qv[c]*k[((size_t)(b*8+c))*HW + j*WD + w];
    if(j == h) e += NEGV;
  } else {
    int jj = j - 64;
    #pragma unroll
    for(int c=0;c<8;c++) e += qv[c]*k[((size_t)(b*8+c))*HW + h*WD + jj];
  }
  ev[j] = e;
  __syncthreads();
  for(int s=64; s>0; s>>=1){ if(j<s) ev[j] = fmaxf(ev[j], ev[j+s]); __syncthreads(); }
  float m = ev[0];
  __syncthreads();
  float p = __expf(e - m);
  ev[j] = p;
  __syncthreads();
  for(int s=64; s>0; s>>=1){ if(j<s) ev[j] += ev[j+s]; __syncthreads(); }
  float inv = 1.0f/ev[0];
  att[(((size_t)(b*HT+h))*WD + w)*128 + j] = p*inv;
}

// ---------- criss-cross aggregation: out = gamma*(outH+outW) + x ----------
// grid (HT, WD, B), block 64 (c)
__global__ __launch_bounds__(64) void k_cc_agg(
    float* __restrict__ out, const float* __restrict__ v, const float* __restrict__ att,
    const float* __restrict__ x, vp gamma, size_t go, const int* dflag)
{
  __shared__ float al[128];
  int f = *dflag;
  int c = threadIdx.x; int h = blockIdx.x; int w = blockIdx.y; int b = blockIdx.z;
  const float* ar = att + (((size_t)(b*HT+h))*WD + w)*128;
  al[c] = ar[c]; al[c+64] = ar[c+64];
  __syncthreads();
  float g = ldf(gamma, go, f);
  const float* vb = v + ((size_t)(b*64+c))*HW;
  float acc = 0.f;
  #pragma unroll 4
  for(int j=0;j<64;j++) acc += vb[(size_t)j*WD + w]*al[j];
  const float* vr = vb + (size_t)h*WD;
  #pragma unroll 4
  for(int j=0;j<64;j++) acc += vr[j]*al[64+j];
  size_t idx = ((size_t)(b*64+c))*HW + (size_t)h*WD + w;
  out[idx] = g*acc + x[idx];
}

// ---------- token transpose for decoder memory: mem_t[b,s,c] ----------
__global__ void k_mk_tokens(float* __restrict__ mem_t, const float* __restrict__ memf)
{
  int c = threadIdx.x; int s = blockIdx.x; int b = blockIdx.y;
  mem_t[((size_t)(b*HW+s))*256 + c] = memf[((size_t)(b*256+c))*HW + s];
}

// ---------- GEMM: Y[M,N] = act(X[M,K] @ W[N,K]^T + bias) ----------
// grid (N/64, ceil(M/64)), block 256; 64x64 tile, BK=16, 4x4 per thread.
// pos2 != null (cross-attn K proj, gm=b*4096+s): X_eff[gm][k] += pos2_NCHW[b,k,s]
__global__ __launch_bounds__(256) void k_gemm(
    float* __restrict__ Y, const float* __restrict__ X, vp W, size_t wo,
    vp bias, size_t bo, vp pos2, int M, int N, int K, int relu, const int* dflag)
{
  __shared__ float Xs[16][68];
  __shared__ float Ws[16][68];
  int f = *dflag;
  int tid = threadIdx.x;
  int bn = blockIdx.x*64, bm = blockIdx.y*64;
  int tx = tid & 15, ty = tid >> 4;
  int mload = tid >> 2;
  int k4 = (tid & 3) * 4;
  float acc[4][4] = {{0}};
  for(int k0=0; k0<K; k0+=16){
    float4 xv = make_float4(0.f,0.f,0.f,0.f);
    int gm = bm + mload;
    if(gm < M){
      xv = *(const float4*)(X + (size_t)gm*K + k0 + k4);
      if(pos2){
        int b = gm >> 12, s = gm & 4095;
        size_t pb = ((size_t)(b*256 + k0 + k4))*HW + s;
        xv.x += ldf(pos2, pb,      f);
        xv.y += ldf(pos2, pb+HW,   f);
        xv.z += ldf(pos2, pb+2*HW, f);
        xv.w += ldf(pos2, pb+3*HW, f);
      }
    }
    Xs[k4+0][mload] = xv.x; Xs[k4+1][mload] = xv.y;
    Xs[k4+2][mload] = xv.z; Xs[k4+3][mload] = xv.w;
    size_t wr = wo + (size_t)(bn + mload)*K + k0 + k4;
    Ws[k4+0][mload] = ldf(W, wr,   f); Ws[k4+1][mload] = ldf(W, wr+1, f);
    Ws[k4+2][mload] = ldf(W, wr+2, f); Ws[k4+3][mload] = ldf(W, wr+3, f);
    __syncthreads();
    #pragma unroll
    for(int kk=0; kk<16; kk++){
      float a0=Xs[kk][ty*4+0], a1=Xs[kk][ty*4+1], a2=Xs[kk][ty*4+2], a3=Xs[kk][ty*4+3];
      float b0=Ws[kk][tx*4+0], b1=Ws[kk][tx*4+1], b2=Ws[kk][tx*4+2], b3=Ws[kk][tx*4+3];
      acc[0][0]+=a0*b0; acc[0][1]+=a0*b1; acc[0][2]+=a0*b2; acc[0][3]+=a0*b3;
      acc[1][0]+=a1*b0; acc[1][1]+=a1*b1; acc[1][2]+=a1*b2; acc[1][3]+=a1*b3;
      acc[2][0]+=a2*b0; acc[2][1]+=a2*b1; acc[2][2]+=a2*b2; acc[2][3]+=a2*b3;
      acc[3][0]+=a3*b0; acc[3][1]+=a3*b1; acc[3][2]+=a3*b2; acc[3][3]+=a3*b3;
    }
    __syncthreads();
  }
  #pragma unroll
  for(int i=0;i<4;i++){
    int m = bm + ty*4 + i;
    if(m >= M) continue;
    #pragma unroll
    for(int j=0;j<4;j++){
      int n = bn + tx*4 + j;
      float vv = acc[i][j] + (bias ? ldf(bias, bo + n, f) : 0.f);
      if(relu) vv = fmaxf(vv, 0.f);
      Y[(size_t)m*N + n] = vv;
    }
  }
}

// ---------- fused attention (one wave per (b,h,l)), online softmax ----------
__global__ __launch_bounds__(64) void k_attn(
    float* __restrict__ out, const float* __restrict__ q,
    const float* __restrict__ k, const float* __restrict__ v,
    int B, int S, size_t bstride, size_t sstride, float scale)
{
  int lane = threadIdx.x;
  int l = blockIdx.x, h = blockIdx.y, b = blockIdx.z;
  const float4* qp = (const float4*)(q + ((size_t)(l*B+b))*256 + h*32);
  float4 qr[8];
  #pragma unroll
  for(int d=0; d<8; d++) qr[d] = qp[d];
  float m = -1e30f, lsum = 0.f;
  float acc[32];
  #pragma unroll
  for(int d=0; d<32; d++) acc[d] = 0.f;
  for(int s=lane; s<S; s+=64){
    const float4* kp = (const float4*)(k + b*bstride + (size_t)s*sstride + h*32);
    const float4* vp2 = (const float4*)(v + b*bstride + (size_t)s*sstride + h*32);
    float e = 0.f;
    #pragma unroll
    for(int d=0; d<8; d++){
      float4 kv = kp[d];
      e += qr[d].x*kv.x + qr[d].y*kv.y + qr[d].z*kv.z + qr[d].w*kv.w;
    }
    e *= scale;
    float nm = fmaxf(m, e);
    float ff = __expf(m - nm);
    float p = __expf(e - nm);
    lsum = lsum*ff + p;
    #pragma unroll
    for(int d=0; d<8; d++){
      float4 vv = vp2[d];
      acc[4*d+0] = acc[4*d+0]*ff + p*vv.x;
      acc[4*d+1] = acc[4*d+1]*ff + p*vv.y;
      acc[4*d+2] = acc[4*d+2]*ff + p*vv.z;
      acc[4*d+3] = acc[4*d+3]*ff + p*vv.w;
    }
    m = nm;
  }
  #pragma unroll
  for(int off=32; off>0; off>>=1){
    float om = __shfl_xor(m, off);
    float ol = __shfl_xor(lsum, off);
    float nm = fmaxf(m, om);
    float fa = __expf(m - nm), fb = __expf(om - nm);
    lsum = lsum*fa + ol*fb;
    #pragma unroll
    for(int d=0; d<32; d++){
      float oa = __shfl_xor(acc[d], off);
      acc[d] = acc[d]*fa + oa*fb;
    }
    m = nm;
  }
  if(lane == 0){
    float inv = 1.0f/lsum;
    float* op = out + ((size_t)(l*B+b))*256 + h*32;
    #pragma unroll
    for(int d=0; d<32; d++) op[d] = acc[d]*inv;
  }
}

// ---------- LayerNorm over C=256 ----------
__global__ __launch_bounds__(256) void k_ln(
    float* dst, const float* x, const float* t2, vp g, vp bb, size_t go, const int* dflag)
{
  __shared__ float red[256];
  int f = *dflag;
  int c = threadIdx.x; int tok = blockIdx.x;
  float v = x[(size_t)tok*256 + c];
  if(t2) v += t2[(size_t)tok*256 + c];
  red[c] = v; __syncthreads();
  for(int s=128; s>0; s>>=1){ if(c<s) red[c] += red[c+s]; __syncthreads(); }
  float mu = red[0]*(1.f/256.f);
  __syncthreads();
  float dv = v - mu;
  red[c] = dv*dv; __syncthreads();
  for(int s=128; s>0; s>>=1){ if(c<s) red[c] += red[c+s]; __syncthreads(); }
  float var = red[0]*(1.f/256.f);
  float r = rsqrtf(var + 1e-5f);
  dst[(size_t)tok*256 + c] = dv*r*ldf(g, go+c, f) + ldf(bb, go+c, f);
}

// ---------- xq = outq + qe (broadcast over batch) ----------
__global__ void k_addqe(float* dst, const float* outq, vp qe, const int* dflag){
  int f = *dflag;
  int c = threadIdx.x; int tok = blockIdx.x; int l = tok >> 2;
  dst[(size_t)tok*256 + c] = outq[(size_t)tok*256 + c] + ldf(qe, (size_t)l*256 + c, f);
}

// ---------- hs writer: hs[0,b,l,c] = lnout[(l*4+b), c] ----------
__global__ void k_write_hs(void* out, const float* lnout, const int* dflag){
  int f = *dflag;
  int c = threadIdx.x; int tok = blockIdx.x; int l = tok >> 2; int b = tok & 3;
  float v = lnout[(size_t)tok*256 + c];
  size_t o = ((size_t)(b*100+l))*256 + c;
  if(f) ((float*)out)[o] = v;
  else  ((__hip_bfloat16*)out)[o] = __float2bfloat16(v);
}

extern "C" void kernel_launch(void* const* d_in, const int* in_sizes, int n_in,
                              void* d_out, int out_size, void* d_ws, size_t ws_size,
                              hipStream_t stream) {
  vp src       = d_in[0];
  // d_in[1] = mask (all false) — unused
  vp query_emb = d_in[2];
  vp pos       = d_in[3];
  vp conva_w   = d_in[4];
  vp q_w = d_in[5];  vp q_b = d_in[6];
  vp k_w = d_in[7];  vp k_b = d_in[8];
  vp v_w = d_in[9];  vp v_b = d_in[10];
  vp gamma = d_in[11];
  vp convb_w = d_in[12];
  vp bneck_w = d_in[13];
  vp sa_in_w = d_in[14];  vp sa_in_b = d_in[15];
  vp sa_out_w = d_in[16]; vp sa_out_b = d_in[17];
  vp ca_in_w = d_in[18];  vp ca_in_b = d_in[19];
  vp ca_out_w = d_in[20]; vp ca_out_b = d_in[21];
  vp lin1_w = d_in[22];   vp lin1_b = d_in[23];
  vp lin2_w = d_in[24];   vp lin2_b = d_in[25];
  vp n1g = d_in[26]; vp n1b = d_in[27];
  vp n2g = d_in[28]; vp n2b = d_in[29];
  vp n3g = d_in[30]; vp n3b = d_in[31];
  vp normg = d_in[32]; vp normb = d_in[33];

  // ---- compact workspace layout (15,532,032 floats + flag = 59.3 MB) ----
  const size_t MEG = 1048576;
  float* ws   = (float*)d_ws;
  float* memf  = ws;                    // 4M floats
  float* xi    = ws + 4*MEG;            // 4M
  float* y64a  = ws + 8*MEG;            // 1M
  float* y64b  = ws + 9*MEG;            // 1M
  float* vb_   = ws + 10*MEG;           // 1M
  float* qb_   = ws + 11*MEG;           // 128K
  float* kb_   = ws + 11*MEG + 131072;  // 128K
  float* attb  = ws + 11*MEG + 262144;  // 2M (ends 13.25M)
  float* y256  = ws + 9*MEG;            // 4M (overlaps dead cc buffers)
  float* mem_t = xi;                    // decoder
  float* kproj = memf;                  // decoder (memf dead after output write)
  float* vproj = ws + 8*MEG;            // decoder
  float* sm    = ws + 13*MEG + 262144;
  float* outq   = sm;
  float* xq     = sm + 102400;
  float* qproj  = sm + 204800;
  float* kself  = sm + 307200;
  float* vself  = sm + 409600;
  float* attout = sm + 512000;
  float* t2     = sm + 614400;
  float* ffn1   = sm + 716800;          // 819200
  float* lnout  = sm + 1536000;         // ends 1,638,400
  int*   dflag  = (int*)(ws + 15532032);

  const int NFULL = 4194304;
  const float scale = 0.17677669529663687f; // 32^-0.5

  k_detect<<<1, 256, 0, stream>>>(dflag, (const unsigned short*)src);
  k_cvt<<<(NFULL+255)/256, 256, 0, stream>>>(memf, src, NFULL, dflag);

  // ------------- encoder -------------
  for(int i=0; i<6; i++){
    k_addpos<<<(NFULL+255)/256, 256, 0, stream>>>(xi, memf, pos, NFULL, dflag);
    k_conv3x3_mfma<<<dim3(64,1,4), 256, 0, stream>>>(y64a, xi, nullptr,
        conva_w, (size_t)i*147456, 256, 0, 64, 1, dflag);
    for(int pass=0; pass<2; pass++){
      const float* cx = pass ? y64b : y64a;
      float* cy       = pass ? y64a : y64b;
      k_conv1x1<<<dim3(64,8,4),  64, 0, stream>>>(qb_, cx, q_w, (size_t)i*512,  q_b, (size_t)i*8,  64, 8,  dflag);
      k_conv1x1<<<dim3(64,8,4),  64, 0, stream>>>(kb_, cx, k_w, (size_t)i*512,  k_b, (size_t)i*8,  64, 8,  dflag);
      k_conv1x1<<<dim3(64,64,4), 64, 0, stream>>>(vb_, cx, v_w, (size_t)i*4096, v_b, (size_t)i*64, 64, 64, dflag);
      k_cc_att<<<dim3(64,64,4), 128, 0, stream>>>(attb, qb_, kb_);
      k_cc_agg<<<dim3(64,64,4), 64, 0, stream>>>(cy, vb_, attb, cx, gamma, (size_t)i, dflag);
    }
    k_conv3x3_mfma<<<dim3(64,4,4), 256, 0, stream>>>(y256, y64a, nullptr,
        convb_w, (size_t)i*147456, 64, 0, 256, 1, dflag);
    k_conv3x3_mfma<<<dim3(64,4,4), 256, 0, stream>>>(memf, xi, y256,
        bneck_w, (size_t)i*1179648, 256, 256, 256, 0, dflag);
  }

  // ------------- decoder prep (before kproj overwrites memf) -------------
  k_mk_tokens<<<dim3(4096,4), 256, 0, stream>>>(mem_t, memf);
  k_write_mem<<<(NFULL+255)/256, 256, 0, stream>>>(d_out, memf, NFULL, dflag);
  k_zero<<<400, 256, 0, stream>>>(outq, 102400);

  // ------------- decoder layers -------------
  for(int i=0; i<6; i++){
    size_t iw = (size_t)i*196608, ib = (size_t)i*768;
    size_t ow = (size_t)i*65536,  ob = (size_t)i*256;
    // self-attention
    k_addqe<<<400, 256, 0, stream>>>(xq, outq, query_emb, dflag);
    k_gemm<<<dim3(4,7), 256, 0, stream>>>(qproj, xq,   sa_in_w, iw,        sa_in_b, ib,     nullptr, 400, 256, 256, 0, dflag);
    k_gemm<<<dim3(4,7), 256, 0, stream>>>(kself, xq,   sa_in_w, iw+65536,  sa_in_b, ib+256, nullptr, 400, 256, 256, 0, dflag);
    k_gemm<<<dim3(4,7), 256, 0, stream>>>(vself, outq, sa_in_w, iw+131072, sa_in_b, ib+512, nullptr, 400, 256, 256, 0, dflag);
    k_attn<<<dim3(100,8,4), 64, 0, stream>>>(attout, qproj, kself, vself,
        4, 100, (size_t)256, (size_t)1024, scale);
    k_gemm<<<dim3(4,7), 256, 0, stream>>>(t2, attout, sa_out_w, ow, sa_out_b, ob, nullptr, 400, 256, 256, 0, dflag);
    k_ln<<<400, 256, 0, stream>>>(outq, outq, t2, n1g, n1b, ob, dflag);
    // cross-attention (K proj fuses +pos)
    k_addqe<<<400, 256, 0, stream>>>(xq, outq, query_emb, dflag);
    k_gemm<<<dim3(4,7),   256, 0, stream>>>(qproj, xq,    ca_in_w, iw,        ca_in_b, ib,     nullptr, 400,   256, 256, 0, dflag);
    k_gemm<<<dim3(4,256), 256, 0, stream>>>(kproj, mem_t, ca_in_w, iw+65536,  ca_in_b, ib+256, pos,     16384, 256, 256, 0, dflag);
    k_gemm<<<dim3(4,256), 256, 0, stream>>>(vproj, mem_t, ca_in_w, iw+131072, ca_in_b, ib+512, nullptr, 16384, 256, 256, 0, dflag);
    k_attn<<<dim3(100,8,4), 64, 0, stream>>>(attout, qproj, kproj, vproj,
        4, 4096, (size_t)1048576, (size_t)256, scale);
    k_gemm<<<dim3(4,7), 256, 0, stream>>>(t2, attout, ca_out_w, ow, ca_out_b, ob, nullptr, 400, 256, 256, 0, dflag);
    k_ln<<<400, 256, 0, stream>>>(outq, outq, t2, n2g, n2b, ob, dflag);
    // FFN
    k_gemm<<<dim3(32,7), 256, 0, stream>>>(ffn1, outq, lin1_w, (size_t)i*524288, lin1_b, (size_t)i*2048, nullptr, 400, 2048, 256, 1, dflag);
    k_gemm<<<dim3(4,7),  256, 0, stream>>>(t2,   ffn1, lin2_w, (size_t)i*524288, lin2_b, ob,             nullptr, 400, 256, 2048, 0, dflag);
    k_ln<<<400, 256, 0, stream>>>(outq, outq, t2, n3g, n3b, ob, dflag);
  }

  // final norm + hs output
  k_ln<<<400, 256, 0, stream>>>(lnout, outq, nullptr, normg, normb, (size_t)0, dflag);
  k_write_hs<<<400, 256, 0, stream>>>(d_out, lnout, dflag);
}

// Round 5
// 10277.470 us; speedup vs baseline: 2.6429x; 1.6318x over previous
//
#include <hip/hip_runtime.h>
#include <hip/hip_bf16.h>

#define HW 4096
#define WD 64
#define HT 64
#define NEGV -1000000000.0f

typedef const void* vp;
typedef __attribute__((ext_vector_type(8))) short bf16x8;
typedef __attribute__((ext_vector_type(4))) float f32x4;

__device__ __forceinline__ float b2f(__hip_bfloat16 v){ return __bfloat162float(v); }
// dtype-dispatched input load: f=1 -> fp32, f=0 -> bf16
__device__ __forceinline__ float ldf(vp p, size_t i, int f){
  return f ? ((const float*)p)[i] : b2f(((const __hip_bfloat16*)p)[i]);
}
__device__ __forceinline__ unsigned short f2b(float x){
  __hip_bfloat16 h = __float2bfloat16(x);
  return *reinterpret_cast<unsigned short*>(&h);
}

// ---------- dtype detector: fp32 data read as u16 has uniform-random low half-words ----------
__global__ void k_detect(int* flag, const unsigned short* p){
  __shared__ int cnt;
  if(threadIdx.x==0) cnt=0;
  __syncthreads();
  int c=0;
  for(int i=threadIdx.x; i<512; i+=256){
    int e = (p[i]>>7)&0xFF;
    if(e>150 || e<100) c++;
  }
  atomicAdd(&cnt, c);
  __syncthreads();
  if(threadIdx.x==0) *flag = (cnt>32) ? 1 : 0;  // 1 = fp32 inputs
}

// ---------- elementwise ----------
__global__ void k_cvt(float* dst, vp src, int n, const int* dflag){
  int f = *dflag;
  int i = blockIdx.x*256 + threadIdx.x;
  if(i<n) dst[i] = ldf(src, i, f);
}

__global__ void k_addpos(float* xi, const float* memf, vp pos, int n, const int* dflag){
  int f = *dflag;
  int i = blockIdx.x*256 + threadIdx.x;
  if(i<n) xi[i] = memf[i] + ldf(pos, i, f);
}

__global__ void k_zero(float* p, int n){
  int i = blockIdx.x*256 + threadIdx.x;
  if(i<n) p[i] = 0.f;
}

// memory_2d writer at element offset 102400 of d_out, dtype per flag
__global__ void k_write_mem(void* out, const float* src, int n, const int* dflag){
  int f = *dflag;
  int i = blockIdx.x*256 + threadIdx.x;
  if(i<n){
    if(f) ((float*)out)[102400 + i] = src[i];
    else  ((__hip_bfloat16*)out)[102400 + i] = __float2bfloat16(src[i]);
  }
}

// ---------- conv weight repack into A-fragment order ----------
// Wp slab layout: slab = (cotile*(Cin/32) + ch)*9 + tap ; within slab 2048 bf16:
//   e = col*32 + ciL  (col = co within tile, ciL = ci within chunk)
// grid = (Cout/64)*(Cin/32)*9 blocks, 256 threads.
__global__ void k_repack(unsigned short* Wp, vp w, size_t wo, int Cin, int Cout, const int* dflag){
  int f = *dflag;
  int slab = blockIdx.x;
  int tap = slab % 9; int t2 = slab / 9;
  int nch = Cin >> 5; int ch = t2 % nch; int cotile = t2 / nch;
  for(int e=threadIdx.x; e<2048; e+=256){
    int col = e >> 5, ciL = e & 31;
    size_t co = cotile*64 + col, ci = ch*32 + ciL;
    float v = ldf(w, wo + (co*Cin + ci)*9 + tap, f);
    Wp[(size_t)slab*2048 + e] = f2b(v);
  }
}

// ---------- 3x3 conv via MFMA implicit GEMM (repacked weights) ----------
// grid (HT, Cout/64, B), block 256 (4 waves). Block: output tile (b, h, 64 co, 64 w).
// A-fragments load straight from Wp (coalesced 1KB per wave). LDS holds only input rows.
__global__ __launch_bounds__(256) void k_conv3x3_mfma(
    float* __restrict__ out, const float* __restrict__ in1, const float* __restrict__ in2,
    const unsigned short* __restrict__ Wp, int Cin1, int Cin2, int Cout, int relu)
{
  __shared__ __attribute__((aligned(16))) unsigned short Xs[3*66*40];  // [kh][w+1][ci32] pad40
  const int tid  = threadIdx.x;
  const int lane = tid & 63;
  const int wv   = tid >> 6;
  const int quad = lane >> 4;
  const int l16  = lane & 15;
  const int h    = blockIdx.x;
  const int cotile = blockIdx.y;
  const int b    = blockIdx.z;
  const int Cin  = Cin1 + Cin2;
  const int nch  = Cin >> 5;

  // zero the w-pad columns (stay zero for whole kernel)
  if(tid < 96){
    int kh = tid>>5, ci = tid&31;
    Xs[(kh*66 + 0)*40 + ci]  = 0;
    Xs[(kh*66 + 65)*40 + ci] = 0;
  }

  f32x4 acc[4];
  #pragma unroll
  for(int nt=0; nt<4; nt++) acc[nt] = (f32x4){0.f,0.f,0.f,0.f};

  // this lane's A-fragment offset inside a slab: co=wv*16+l16 (m), ci=quad*8 (k)
  const unsigned short* wlane = Wp + ((size_t)cotile*nch)*9*2048 + (wv*16+l16)*32 + quad*8;

  for(int ch=0; ch<nch; ch++){
    __syncthreads();
    // ---- stage input rows h-1..h+1 for this ci chunk: Xs[kh][w+1][ci] ----
    #pragma unroll
    for(int it=0; it<6; it++){
      int t   = it*256 + tid;       // 0..1535
      int kh  = t >> 9;
      int rem = t & 511;
      int ci  = rem >> 4;
      int w4  = (rem & 15) << 2;
      int r   = h + kh - 1;
      float4 xv = make_float4(0.f,0.f,0.f,0.f);
      int cg = ch*32 + ci;
      if(r >= 0 && r < HT){
        const float* srcp = (cg < Cin1) ? in1 + ((size_t)(b*Cin1+cg))*HW
                                        : in2 + ((size_t)(b*Cin2+(cg-Cin1)))*HW;
        xv = *(const float4*)(srcp + r*WD + w4);
      }
      int base = (kh*66 + w4 + 1)*40 + ci;
      Xs[base]      = f2b(xv.x);
      Xs[base+40]   = f2b(xv.y);
      Xs[base+80]   = f2b(xv.z);
      Xs[base+120]  = f2b(xv.w);
    }
    __syncthreads();
    // ---- MFMA over 9 taps; A from global (L2), B from LDS ----
    const unsigned short* wch = wlane + (size_t)ch*9*2048;
    #pragma unroll
    for(int tap=0; tap<9; tap++){
      const int kh = tap/3, kw = tap%3;
      bf16x8 af = *(const bf16x8*)(wch + tap*2048);
      #pragma unroll
      for(int nt=0; nt<4; nt++){
        bf16x8 bfr = *(const bf16x8*)&Xs[(kh*66 + nt*16 + l16 + kw)*40 + quad*8];
        acc[nt] = __builtin_amdgcn_mfma_f32_16x16x32_bf16(af, bfr, acc[nt], 0, 0, 0);
      }
    }
  }
  // ---- epilogue: D row = quad*4+r (co), col = l16 (w) ----
  #pragma unroll
  for(int nt=0; nt<4; nt++){
    #pragma unroll
    for(int r=0; r<4; r++){
      float vv = acc[nt][r];
      if(relu) vv = fmaxf(vv, 0.f);
      out[((size_t)(b*Cout + cotile*64 + wv*16 + quad*4 + r))*HW + h*WD + nt*16 + l16] = vv;
    }
  }
}

// ---------- 1x1 conv with bias (Cin<=64) ----------
// grid (HW/64, Cout, B), block 64
__global__ __launch_bounds__(64) void k_conv1x1(
    float* __restrict__ out, const float* __restrict__ in, vp w, size_t wo,
    vp bias, size_t bo, int Cin, int Cout, const int* dflag)
{
  __shared__ float wl[64];
  int f = *dflag;
  int tid = threadIdx.x; int co = blockIdx.y; int b = blockIdx.z;
  int p = blockIdx.x*64 + tid;
  for(int i=tid; i<Cin; i+=64) wl[i] = ldf(w, wo + (size_t)co*Cin + i, f);
  __syncthreads();
  float acc = ldf(bias, bo + co, f);
  for(int c=0; c<Cin; c++) acc += in[((size_t)(b*Cin+c))*HW + p]*wl[c];
  out[((size_t)(b*Cout+co))*HW + p] = acc;
}

// ---------- criss-cross energies + softmax ----------
// grid (WD, HT, B), block 128.
__global__ __launch_bounds__(128) void k_cc_att(
    float* __restrict__ att, const float* __restrict__ q, const float* __restrict__ k)
{
  __shared__ float qv[8];
  __shared__ float ev[128];
  int j = threadIdx.x; int w = blockIdx.x; int h = blockIdx.y; int b = blockIdx.z;
  if(j < 8) qv[j] = q[((size_t)(b*8+j))*HW + h*WD + w];
  __syncthreads();
  float e = 0.f;
  if(j < 64){
    #pragma unroll
    for(int c=0;c<8;c++) e += qv[c]*k[((size_t)(b*8+c))*HW + j*WD + w];
    if(j == h) e += NEGV;
  } else {
    int jj = j - 64;
    #pragma unroll
    for(int c=0;c<8;c++) e += qv[c]*k[((size_t)(b*8+c))*HW + h*WD + jj];
  }
  ev[j] = e;
  __syncthreads();
  for(int s=64; s>0; s>>=1){ if(j<s) ev[j] = fmaxf(ev[j], ev[j+s]); __syncthreads(); }
  float m = ev[0];
  __syncthreads();
  float p = __expf(e - m);
  ev[j] = p;
  __syncthreads();
  for(int s=64; s>0; s>>=1){ if(j<s) ev[j] += ev[j+s]; __syncthreads(); }
  float inv = 1.0f/ev[0];
  att[(((size_t)(b*HT+h))*WD + w)*128 + j] = p*inv;
}

// ---------- criss-cross aggregation: out = gamma*(outH+outW) + x ----------
// grid (HT, WD, B), block 64 (c)
__global__ __launch_bounds__(64) void k_cc_agg(
    float* __restrict__ out, const float* __restrict__ v, const float* __restrict__ att,
    const float* __restrict__ x, vp gamma, size_t go, const int* dflag)
{
  __shared__ float al[128];
  int f = *dflag;
  int c = threadIdx.x; int h = blockIdx.x; int w = blockIdx.y; int b = blockIdx.z;
  const float* ar = att + (((size_t)(b*HT+h))*WD + w)*128;
  al[c] = ar[c]; al[c+64] = ar[c+64];
  __syncthreads();
  float g = ldf(gamma, go, f);
  const float* vb = v + ((size_t)(b*64+c))*HW;
  float acc = 0.f;
  #pragma unroll 4
  for(int j=0;j<64;j++) acc += vb[(size_t)j*WD + w]*al[j];
  const float* vr = vb + (size_t)h*WD;
  #pragma unroll 4
  for(int j=0;j<64;j++) acc += vr[j]*al[64+j];
  size_t idx = ((size_t)(b*64+c))*HW + (size_t)h*WD + w;
  out[idx] = g*acc + x[idx];
}

// ---------- token transpose for decoder memory: mem_t[b,s,c] ----------
__global__ void k_mk_tokens(float* __restrict__ mem_t, const float* __restrict__ memf)
{
  int c = threadIdx.x; int s = blockIdx.x; int b = blockIdx.y;
  mem_t[((size_t)(b*HW+s))*256 + c] = memf[((size_t)(b*256+c))*HW + s];
}

// ---------- GEMM: Y[M,N] = act(X[M,K] @ W[N,K]^T + bias) ----------
// grid (N/64, ceil(M/64)), block 256; 64x64 tile, BK=16, 4x4 per thread.
// pos2 != null (cross-attn K proj, gm=b*4096+s): X_eff[gm][k] += pos2_NCHW[b,k,s]
__global__ __launch_bounds__(256) void k_gemm(
    float* __restrict__ Y, const float* __restrict__ X, vp W, size_t wo,
    vp bias, size_t bo, vp pos2, int M, int N, int K, int relu, const int* dflag)
{
  __shared__ float Xs[16][68];
  __shared__ float Ws[16][68];
  int f = *dflag;
  int tid = threadIdx.x;
  int bn = blockIdx.x*64, bm = blockIdx.y*64;
  int tx = tid & 15, ty = tid >> 4;
  int mload = tid >> 2;
  int k4 = (tid & 3) * 4;
  float acc[4][4] = {{0}};
  for(int k0=0; k0<K; k0+=16){
    float4 xv = make_float4(0.f,0.f,0.f,0.f);
    int gm = bm + mload;
    if(gm < M){
      xv = *(const float4*)(X + (size_t)gm*K + k0 + k4);
      if(pos2){
        int b = gm >> 12, s = gm & 4095;
        size_t pb = ((size_t)(b*256 + k0 + k4))*HW + s;
        xv.x += ldf(pos2, pb,      f);
        xv.y += ldf(pos2, pb+HW,   f);
        xv.z += ldf(pos2, pb+2*HW, f);
        xv.w += ldf(pos2, pb+3*HW, f);
      }
    }
    Xs[k4+0][mload] = xv.x; Xs[k4+1][mload] = xv.y;
    Xs[k4+2][mload] = xv.z; Xs[k4+3][mload] = xv.w;
    size_t wr = wo + (size_t)(bn + mload)*K + k0 + k4;
    Ws[k4+0][mload] = ldf(W, wr,   f); Ws[k4+1][mload] = ldf(W, wr+1, f);
    Ws[k4+2][mload] = ldf(W, wr+2, f); Ws[k4+3][mload] = ldf(W, wr+3, f);
    __syncthreads();
    #pragma unroll
    for(int kk=0; kk<16; kk++){
      float a0=Xs[kk][ty*4+0], a1=Xs[kk][ty*4+1], a2=Xs[kk][ty*4+2], a3=Xs[kk][ty*4+3];
      float b0=Ws[kk][tx*4+0], b1=Ws[kk][tx*4+1], b2=Ws[kk][tx*4+2], b3=Ws[kk][tx*4+3];
      acc[0][0]+=a0*b0; acc[0][1]+=a0*b1; acc[0][2]+=a0*b2; acc[0][3]+=a0*b3;
      acc[1][0]+=a1*b0; acc[1][1]+=a1*b1; acc[1][2]+=a1*b2; acc[1][3]+=a1*b3;
      acc[2][0]+=a2*b0; acc[2][1]+=a2*b1; acc[2][2]+=a2*b2; acc[2][3]+=a2*b3;
      acc[3][0]+=a3*b0; acc[3][1]+=a3*b1; acc[3][2]+=a3*b2; acc[3][3]+=a3*b3;
    }
    __syncthreads();
  }
  #pragma unroll
  for(int i=0;i<4;i++){
    int m = bm + ty*4 + i;
    if(m >= M) continue;
    #pragma unroll
    for(int j=0;j<4;j++){
      int n = bn + tx*4 + j;
      float vv = acc[i][j] + (bias ? ldf(bias, bo + n, f) : 0.f);
      if(relu) vv = fmaxf(vv, 0.f);
      Y[(size_t)m*N + n] = vv;
    }
  }
}

// ---------- fused attention (one wave per (b,h,l)), online softmax ----------
__global__ __launch_bounds__(64) void k_attn(
    float* __restrict__ out, const float* __restrict__ q,
    const float* __restrict__ k, const float* __restrict__ v,
    int B, int S, size_t bstride, size_t sstride, float scale)
{
  int lane = threadIdx.x;
  int l = blockIdx.x, h = blockIdx.y, b = blockIdx.z;
  const float4* qp = (const float4*)(q + ((size_t)(l*B+b))*256 + h*32);
  float4 qr[8];
  #pragma unroll
  for(int d=0; d<8; d++) qr[d] = qp[d];
  float m = -1e30f, lsum = 0.f;
  float acc[32];
  #pragma unroll
  for(int d=0; d<32; d++) acc[d] = 0.f;
  for(int s=lane; s<S; s+=64){
    const float4* kp = (const float4*)(k + b*bstride + (size_t)s*sstride + h*32);
    const float4* vp2 = (const float4*)(v + b*bstride + (size_t)s*sstride + h*32);
    float e = 0.f;
    #pragma unroll
    for(int d=0; d<8; d++){
      float4 kv = kp[d];
      e += qr[d].x*kv.x + qr[d].y*kv.y + qr[d].z*kv.z + qr[d].w*kv.w;
    }
    e *= scale;
    float nm = fmaxf(m, e);
    float ff = __expf(m - nm);
    float p = __expf(e - nm);
    lsum = lsum*ff + p;
    #pragma unroll
    for(int d=0; d<8; d++){
      float4 vv = vp2[d];
      acc[4*d+0] = acc[4*d+0]*ff + p*vv.x;
      acc[4*d+1] = acc[4*d+1]*ff + p*vv.y;
      acc[4*d+2] = acc[4*d+2]*ff + p*vv.z;
      acc[4*d+3] = acc[4*d+3]*ff + p*vv.w;
    }
    m = nm;
  }
  #pragma unroll
  for(int off=32; off>0; off>>=1){
    float om = __shfl_xor(m, off);
    float ol = __shfl_xor(lsum, off);
    float nm = fmaxf(m, om);
    float fa = __expf(m - nm), fb = __expf(om - nm);
    lsum = lsum*fa + ol*fb;
    #pragma unroll
    for(int d=0; d<32; d++){
      float oa = __shfl_xor(acc[d], off);
      acc[d] = acc[d]*fa + oa*fb;
    }
    m = nm;
  }
  if(lane == 0){
    float inv = 1.0f/lsum;
    float* op = out + ((size_t)(l*B+b))*256 + h*32;
    #pragma unroll
    for(int d=0; d<32; d++) op[d] = acc[d]*inv;
  }
}

// ---------- LayerNorm over C=256 ----------
__global__ __launch_bounds__(256) void k_ln(
    float* dst, const float* x, const float* t2, vp g, vp bb, size_t go, const int* dflag)
{
  __shared__ float red[256];
  int f = *dflag;
  int c = threadIdx.x; int tok = blockIdx.x;
  float v = x[(size_t)tok*256 + c];
  if(t2) v += t2[(size_t)tok*256 + c];
  red[c] = v; __syncthreads();
  for(int s=128; s>0; s>>=1){ if(c<s) red[c] += red[c+s]; __syncthreads(); }
  float mu = red[0]*(1.f/256.f);
  __syncthreads();
  float dv = v - mu;
  red[c] = dv*dv; __syncthreads();
  for(int s=128; s>0; s>>=1){ if(c<s) red[c] += red[c+s]; __syncthreads(); }
  float var = red[0]*(1.f/256.f);
  float r = rsqrtf(var + 1e-5f);
  dst[(size_t)tok*256 + c] = dv*r*ldf(g, go+c, f) + ldf(bb, go+c, f);
}

// ---------- xq = outq + qe (broadcast over batch) ----------
__global__ void k_addqe(float* dst, const float* outq, vp qe, const int* dflag){
  int f = *dflag;
  int c = threadIdx.x; int tok = blockIdx.x; int l = tok >> 2;
  dst[(size_t)tok*256 + c] = outq[(size_t)tok*256 + c] + ldf(qe, (size_t)l*256 + c, f);
}

// ---------- hs writer: hs[0,b,l,c] = lnout[(l*4+b), c] ----------
__global__ void k_write_hs(void* out, const float* lnout, const int* dflag){
  int f = *dflag;
  int c = threadIdx.x; int tok = blockIdx.x; int l = tok >> 2; int b = tok & 3;
  float v = lnout[(size_t)tok*256 + c];
  size_t o = ((size_t)(b*100+l))*256 + c;
  if(f) ((float*)out)[o] = v;
  else  ((__hip_bfloat16*)out)[o] = __float2bfloat16(v);
}

extern "C" void kernel_launch(void* const* d_in, const int* in_sizes, int n_in,
                              void* d_out, int out_size, void* d_ws, size_t ws_size,
                              hipStream_t stream) {
  vp src       = d_in[0];
  // d_in[1] = mask (all false) — unused
  vp query_emb = d_in[2];
  vp pos       = d_in[3];
  vp conva_w   = d_in[4];
  vp q_w = d_in[5];  vp q_b = d_in[6];
  vp k_w = d_in[7];  vp k_b = d_in[8];
  vp v_w = d_in[9];  vp v_b = d_in[10];
  vp gamma = d_in[11];
  vp convb_w = d_in[12];
  vp bneck_w = d_in[13];
  vp sa_in_w = d_in[14];  vp sa_in_b = d_in[15];
  vp sa_out_w = d_in[16]; vp sa_out_b = d_in[17];
  vp ca_in_w = d_in[18];  vp ca_in_b = d_in[19];
  vp ca_out_w = d_in[20]; vp ca_out_b = d_in[21];
  vp lin1_w = d_in[22];   vp lin1_b = d_in[23];
  vp lin2_w = d_in[24];   vp lin2_b = d_in[25];
  vp n1g = d_in[26]; vp n1b = d_in[27];
  vp n2g = d_in[28]; vp n2b = d_in[29];
  vp n3g = d_in[30]; vp n3b = d_in[31];
  vp normg = d_in[32]; vp normb = d_in[33];

  // ---- workspace layout (16,122,112 floats ≈ 61.5 MB) ----
  const size_t MEG = 1048576;
  float* ws   = (float*)d_ws;
  float* memf  = ws;                    // 4M floats
  float* xi    = ws + 4*MEG;            // 4M
  float* y64a  = ws + 8*MEG;            // 1M
  float* y64b  = ws + 9*MEG;            // 1M
  float* vb_   = ws + 10*MEG;           // 1M
  float* qb_   = ws + 11*MEG;           // 128K
  float* kb_   = ws + 11*MEG + 131072;  // 128K
  float* attb  = ws + 11*MEG + 262144;  // 2M (ends 13.25M)
  float* y256  = ws + 9*MEG;            // 4M (overlaps dead cc buffers)
  float* mem_t = xi;                    // decoder
  float* kproj = memf;                  // decoder (memf dead after output write)
  float* vproj = ws + 8*MEG;            // decoder
  float* sm    = ws + 13*MEG + 262144;
  float* outq   = sm;
  float* xq     = sm + 102400;
  float* qproj  = sm + 204800;
  float* kself  = sm + 307200;
  float* vself  = sm + 409600;
  float* attout = sm + 512000;
  float* t2     = sm + 614400;
  float* ffn1   = sm + 716800;          // 819200
  float* lnout  = sm + 1536000;         // ends 1,638,400 -> ws offset 15,532,032
  unsigned short* Wp = (unsigned short*)(ws + 15532032);  // 1,179,648 ushorts = 589,824 floats
  int*   dflag  = (int*)(ws + 15532032 + 589824);

  const int NFULL = 4194304;
  const float scale = 0.17677669529663687f; // 32^-0.5

  k_detect<<<1, 256, 0, stream>>>(dflag, (const unsigned short*)src);
  k_cvt<<<(NFULL+255)/256, 256, 0, stream>>>(memf, src, NFULL, dflag);

  // ------------- encoder -------------
  for(int i=0; i<6; i++){
    k_addpos<<<(NFULL+255)/256, 256, 0, stream>>>(xi, memf, pos, NFULL, dflag);
    // conva: Cin=256, Cout=64
    k_repack<<<72, 256, 0, stream>>>(Wp, conva_w, (size_t)i*147456, 256, 64, dflag);
    k_conv3x3_mfma<<<dim3(64,1,4), 256, 0, stream>>>(y64a, xi, nullptr, Wp, 256, 0, 64, 1);
    for(int pass=0; pass<2; pass++){
      const float* cx = pass ? y64b : y64a;
      float* cy       = pass ? y64a : y64b;
      k_conv1x1<<<dim3(64,8,4),  64, 0, stream>>>(qb_, cx, q_w, (size_t)i*512,  q_b, (size_t)i*8,  64, 8,  dflag);
      k_conv1x1<<<dim3(64,8,4),  64, 0, stream>>>(kb_, cx, k_w, (size_t)i*512,  k_b, (size_t)i*8,  64, 8,  dflag);
      k_conv1x1<<<dim3(64,64,4), 64, 0, stream>>>(vb_, cx, v_w, (size_t)i*4096, v_b, (size_t)i*64, 64, 64, dflag);
      k_cc_att<<<dim3(64,64,4), 128, 0, stream>>>(attb, qb_, kb_);
      k_cc_agg<<<dim3(64,64,4), 64, 0, stream>>>(cy, vb_, attb, cx, gamma, (size_t)i, dflag);
    }
    // convb: Cin=64, Cout=256
    k_repack<<<72, 256, 0, stream>>>(Wp, convb_w, (size_t)i*147456, 64, 256, dflag);
    k_conv3x3_mfma<<<dim3(64,4,4), 256, 0, stream>>>(y256, y64a, nullptr, Wp, 64, 0, 256, 1);
    // bneck: Cin=512 (concat), Cout=256
    k_repack<<<576, 256, 0, stream>>>(Wp, bneck_w, (size_t)i*1179648, 512, 256, dflag);
    k_conv3x3_mfma<<<dim3(64,4,4), 256, 0, stream>>>(memf, xi, y256, Wp, 256, 256, 256, 0);
  }

  // ------------- decoder prep (before kproj overwrites memf) -------------
  k_mk_tokens<<<dim3(4096,4), 256, 0, stream>>>(mem_t, memf);
  k_write_mem<<<(NFULL+255)/256, 256, 0, stream>>>(d_out, memf, NFULL, dflag);
  k_zero<<<400, 256, 0, stream>>>(outq, 102400);

  // ------------- decoder layers -------------
  for(int i=0; i<6; i++){
    size_t iw = (size_t)i*196608, ib = (size_t)i*768;
    size_t ow = (size_t)i*65536,  ob = (size_t)i*256;
    // self-attention
    k_addqe<<<400, 256, 0, stream>>>(xq, outq, query_emb, dflag);
    k_gemm<<<dim3(4,7), 256, 0, stream>>>(qproj, xq,   sa_in_w, iw,        sa_in_b, ib,     nullptr, 400, 256, 256, 0, dflag);
    k_gemm<<<dim3(4,7), 256, 0, stream>>>(kself, xq,   sa_in_w, iw+65536,  sa_in_b, ib+256, nullptr, 400, 256, 256, 0, dflag);
    k_gemm<<<dim3(4,7), 256, 0, stream>>>(vself, outq, sa_in_w, iw+131072, sa_in_b, ib+512, nullptr, 400, 256, 256, 0, dflag);
    k_attn<<<dim3(100,8,4), 64, 0, stream>>>(attout, qproj, kself, vself,
        4, 100, (size_t)256, (size_t)1024, scale);
    k_gemm<<<dim3(4,7), 256, 0, stream>>>(t2, attout, sa_out_w, ow, sa_out_b, ob, nullptr, 400, 256, 256, 0, dflag);
    k_ln<<<400, 256, 0, stream>>>(outq, outq, t2, n1g, n1b, ob, dflag);
    // cross-attention (K proj fuses +pos)
    k_addqe<<<400, 256, 0, stream>>>(xq, outq, query_emb, dflag);
    k_gemm<<<dim3(4,7),   256, 0, stream>>>(qproj, xq,    ca_in_w, iw,        ca_in_b, ib,     nullptr, 400,   256, 256, 0, dflag);
    k_gemm<<<dim3(4,256), 256, 0, stream>>>(kproj, mem_t, ca_in_w, iw+65536,  ca_in_b, ib+256, pos,     16384, 256, 256, 0, dflag);
    k_gemm<<<dim3(4,256), 256, 0, stream>>>(vproj, mem_t, ca_in_w, iw+131072, ca_in_b, ib+512, nullptr, 16384, 256, 256, 0, dflag);
    k_attn<<<dim3(100,8,4), 64, 0, stream>>>(attout, qproj, kproj, vproj,
        4, 4096, (size_t)1048576, (size_t)256, scale);
    k_gemm<<<dim3(4,7), 256, 0, stream>>>(t2, attout, ca_out_w, ow, ca_out_b, ob, nullptr, 400, 256, 256, 0, dflag);
    k_ln<<<400, 256, 0, stream>>>(outq, outq, t2, n2g, n2b, ob, dflag);
    // FFN
    k_gemm<<<dim3(32,7), 256, 0, stream>>>(ffn1, outq, lin1_w, (size_t)i*524288, lin1_b, (size_t)i*2048, nullptr, 400, 2048, 256, 1, dflag);
    k_gemm<<<dim3(4,7),  256, 0, stream>>>(t2,   ffn1, lin2_w, (size_t)i*524288, lin2_b, ob,             nullptr, 400, 256, 2048, 0, dflag);
    k_ln<<<400, 256, 0, stream>>>(outq, outq, t2, n3g, n3b, ob, dflag);
  }

  // final norm + hs output
  k_ln<<<400, 256, 0, stream>>>(lnout, outq, nullptr, normg, normb, (size_t)0, dflag);
  k_write_hs<<<400, 256, 0, stream>>>(d_out, lnout, dflag);
}

// Round 6
// 8336.912 us; speedup vs baseline: 3.2580x; 1.2328x over previous
//
#include <hip/hip_runtime.h>
#include <hip/hip_bf16.h>

#define HW 4096
#define WD 64
#define HT 64
#define NEGV -1000000000.0f

typedef const void* vp;
typedef __attribute__((ext_vector_type(8))) short bf16x8;
typedef __attribute__((ext_vector_type(8))) unsigned short ushort8;
typedef __attribute__((ext_vector_type(4))) float f32x4;

__device__ __forceinline__ float b2f(__hip_bfloat16 v){ return __bfloat162float(v); }
__device__ __forceinline__ float ldf(vp p, size_t i, int f){
  return f ? ((const float*)p)[i] : b2f(((const __hip_bfloat16*)p)[i]);
}
__device__ __forceinline__ unsigned short f2b(float x){
  __hip_bfloat16 h = __float2bfloat16(x);
  return *reinterpret_cast<unsigned short*>(&h);
}
__device__ __forceinline__ float u2f(unsigned short u){
  union { unsigned int i; float f; } x; x.i = ((unsigned int)u) << 16; return x.f;
}

// ---------- dtype detector ----------
__global__ void k_detect(int* flag, const unsigned short* p){
  __shared__ int cnt;
  if(threadIdx.x==0) cnt=0;
  __syncthreads();
  int c=0;
  for(int i=threadIdx.x; i<512; i+=256){
    int e = (p[i]>>7)&0xFF;
    if(e>150 || e<100) c++;
  }
  atomicAdd(&cnt, c);
  __syncthreads();
  if(threadIdx.x==0) *flag = (cnt>32) ? 1 : 0;  // 1 = fp32 inputs
}

// ---------- elementwise ----------
__global__ void k_cvt(float* dst, vp src, int n, const int* dflag){
  int f = *dflag;
  int i = blockIdx.x*256 + threadIdx.x;
  if(i<n) dst[i] = ldf(src, i, f);
}

__global__ void k_addpos(float* xi, const float* memf, vp pos, int n, const int* dflag){
  int f = *dflag;
  int i = blockIdx.x*256 + threadIdx.x;
  if(i<n) xi[i] = memf[i] + ldf(pos, i, f);
}

__global__ void k_zero(float* p, int n){
  int i = blockIdx.x*256 + threadIdx.x;
  if(i<n) p[i] = 0.f;
}

__global__ void k_write_mem(void* out, const float* src, int n, const int* dflag){
  int f = *dflag;
  int i = blockIdx.x*256 + threadIdx.x;
  if(i<n){
    if(f) ((float*)out)[102400 + i] = src[i];
    else  ((__hip_bfloat16*)out)[102400 + i] = __float2bfloat16(src[i]);
  }
}

// ---------- conv weight repack into A-fragment order ----------
__global__ void k_repack(unsigned short* Wp, vp w, size_t wo, int Cin, int Cout, const int* dflag){
  int f = *dflag;
  int slab = blockIdx.x;
  int tap = slab % 9; int t2 = slab / 9;
  int nch = Cin >> 5; int ch = t2 % nch; int cotile = t2 / nch;
  for(int e=threadIdx.x; e<2048; e+=256){
    int col = e >> 5, ciL = e & 31;
    size_t co = cotile*64 + col, ci = ch*32 + ciL;
    float v = ldf(w, wo + (co*Cin + ci)*9 + tap, f);
    Wp[(size_t)slab*2048 + e] = f2b(v);
  }
}

// ---------- 3x3 conv via MFMA implicit GEMM (repacked weights) ----------
__global__ __launch_bounds__(256) void k_conv3x3_mfma(
    float* __restrict__ out, const float* __restrict__ in1, const float* __restrict__ in2,
    const unsigned short* __restrict__ Wp, int Cin1, int Cin2, int Cout, int relu)
{
  __shared__ __attribute__((aligned(16))) unsigned short Xs[3*66*40];
  const int tid  = threadIdx.x;
  const int lane = tid & 63;
  const int wv   = tid >> 6;
  const int quad = lane >> 4;
  const int l16  = lane & 15;
  const int h    = blockIdx.x;
  const int cotile = blockIdx.y;
  const int b    = blockIdx.z;
  const int Cin  = Cin1 + Cin2;
  const int nch  = Cin >> 5;

  if(tid < 96){
    int kh = tid>>5, ci = tid&31;
    Xs[(kh*66 + 0)*40 + ci]  = 0;
    Xs[(kh*66 + 65)*40 + ci] = 0;
  }

  f32x4 acc[4];
  #pragma unroll
  for(int nt=0; nt<4; nt++) acc[nt] = (f32x4){0.f,0.f,0.f,0.f};

  const unsigned short* wlane = Wp + ((size_t)cotile*nch)*9*2048 + (wv*16+l16)*32 + quad*8;

  for(int ch=0; ch<nch; ch++){
    __syncthreads();
    #pragma unroll
    for(int it=0; it<6; it++){
      int t   = it*256 + tid;
      int kh  = t >> 9;
      int rem = t & 511;
      int ci  = rem >> 4;
      int w4  = (rem & 15) << 2;
      int r   = h + kh - 1;
      float4 xv = make_float4(0.f,0.f,0.f,0.f);
      int cg = ch*32 + ci;
      if(r >= 0 && r < HT){
        const float* srcp = (cg < Cin1) ? in1 + ((size_t)(b*Cin1+cg))*HW
                                        : in2 + ((size_t)(b*Cin2+(cg-Cin1)))*HW;
        xv = *(const float4*)(srcp + r*WD + w4);
      }
      int base = (kh*66 + w4 + 1)*40 + ci;
      Xs[base]      = f2b(xv.x);
      Xs[base+40]   = f2b(xv.y);
      Xs[base+80]   = f2b(xv.z);
      Xs[base+120]  = f2b(xv.w);
    }
    __syncthreads();
    const unsigned short* wch = wlane + (size_t)ch*9*2048;
    #pragma unroll
    for(int tap=0; tap<9; tap++){
      const int kh = tap/3, kw = tap%3;
      bf16x8 af = *(const bf16x8*)(wch + tap*2048);
      #pragma unroll
      for(int nt=0; nt<4; nt++){
        bf16x8 bfr = *(const bf16x8*)&Xs[(kh*66 + nt*16 + l16 + kw)*40 + quad*8];
        acc[nt] = __builtin_amdgcn_mfma_f32_16x16x32_bf16(af, bfr, acc[nt], 0, 0, 0);
      }
    }
  }
  #pragma unroll
  for(int nt=0; nt<4; nt++){
    #pragma unroll
    for(int r=0; r<4; r++){
      float vv = acc[nt][r];
      if(relu) vv = fmaxf(vv, 0.f);
      out[((size_t)(b*Cout + cotile*64 + wv*16 + quad*4 + r))*HW + h*WD + nt*16 + l16] = vv;
    }
  }
}

// ---------- MFMA GEMM with bf16 output: Y[M,N] = X_f32[M,K] @ W[N,K]^T + bias ----------
// grid (N/64, M/64), block 256. BK=32. Optional pos2 (NCHW bf16/f32) added to X (gm=b*4096+s).
__global__ __launch_bounds__(256) void k_gemm_mfma(
    __hip_bfloat16* __restrict__ Y, const float* __restrict__ X, vp W, size_t wo,
    vp bias, size_t bo, vp pos2, int M, int N, int K, const int* dflag)
{
  __shared__ __attribute__((aligned(16))) unsigned short Xs[64*40];
  __shared__ __attribute__((aligned(16))) unsigned short Ws[64*40];
  const int f = *dflag;
  const int tid = threadIdx.x;
  const int bn = blockIdx.x*64, bm = blockIdx.y*64;
  const int lane = tid & 63, wv = tid >> 6, quad = lane >> 4, l16 = lane & 15;
  const int row = tid >> 2, kq = (tid & 3) * 8;

  f32x4 acc[4];
  #pragma unroll
  for(int mt=0; mt<4; mt++) acc[mt] = (f32x4){0.f,0.f,0.f,0.f};

  for(int k0=0; k0<K; k0+=32){
    __syncthreads();
    // stage X (fp32 -> bf16), with optional pos add
    {
      int gm = bm + row;
      const float* xp = X + (size_t)gm*K + k0 + kq;
      float4 xa = *(const float4*)xp;
      float4 xb = *(const float4*)(xp+4);
      if(pos2){
        int b = gm >> 12, s = gm & 4095;
        size_t pb = ((size_t)(b*256 + k0 + kq))*HW + s;
        xa.x += ldf(pos2, pb,      f); xa.y += ldf(pos2, pb+HW,   f);
        xa.z += ldf(pos2, pb+2*HW, f); xa.w += ldf(pos2, pb+3*HW, f);
        xb.x += ldf(pos2, pb+4*HW, f); xb.y += ldf(pos2, pb+5*HW, f);
        xb.z += ldf(pos2, pb+6*HW, f); xb.w += ldf(pos2, pb+7*HW, f);
      }
      ushort8 xo;
      xo[0]=f2b(xa.x); xo[1]=f2b(xa.y); xo[2]=f2b(xa.z); xo[3]=f2b(xa.w);
      xo[4]=f2b(xb.x); xo[5]=f2b(xb.y); xo[6]=f2b(xb.z); xo[7]=f2b(xb.w);
      *(ushort8*)&Xs[row*40 + kq] = xo;
    }
    // stage W
    {
      size_t wr = wo + (size_t)(bn + row)*K + k0 + kq;
      ushort8 wo8;
      if(f){
        const float* wp2 = (const float*)W + wr;
        float4 wa = *(const float4*)wp2;
        float4 wb = *(const float4*)(wp2+4);
        wo8[0]=f2b(wa.x); wo8[1]=f2b(wa.y); wo8[2]=f2b(wa.z); wo8[3]=f2b(wa.w);
        wo8[4]=f2b(wb.x); wo8[5]=f2b(wb.y); wo8[6]=f2b(wb.z); wo8[7]=f2b(wb.w);
      } else {
        wo8 = *(const ushort8*)((const unsigned short*)W + wr);
      }
      *(ushort8*)&Ws[row*40 + kq] = wo8;
    }
    __syncthreads();
    bf16x8 bfr = *(const bf16x8*)&Ws[(wv*16 + l16)*40 + quad*8];
    #pragma unroll
    for(int mt=0; mt<4; mt++){
      bf16x8 af = *(const bf16x8*)&Xs[(mt*16 + l16)*40 + quad*8];
      acc[mt] = __builtin_amdgcn_mfma_f32_16x16x32_bf16(af, bfr, acc[mt], 0, 0, 0);
    }
  }
  const int n = bn + wv*16 + l16;
  const float bv = ldf(bias, bo + n, f);
  #pragma unroll
  for(int mt=0; mt<4; mt++){
    #pragma unroll
    for(int r=0; r<4; r++){
      int m = bm + mt*16 + quad*4 + r;
      Y[(size_t)m*N + n] = __float2bfloat16(acc[mt][r] + bv);
    }
  }
}

// ---------- 1x1 conv with bias (Cin<=64) ----------
__global__ __launch_bounds__(64) void k_conv1x1(
    float* __restrict__ out, const float* __restrict__ in, vp w, size_t wo,
    vp bias, size_t bo, int Cin, int Cout, const int* dflag)
{
  __shared__ float wl[64];
  int f = *dflag;
  int tid = threadIdx.x; int co = blockIdx.y; int b = blockIdx.z;
  int p = blockIdx.x*64 + tid;
  for(int i=tid; i<Cin; i+=64) wl[i] = ldf(w, wo + (size_t)co*Cin + i, f);
  __syncthreads();
  float acc = ldf(bias, bo + co, f);
  for(int c=0; c<Cin; c++) acc += in[((size_t)(b*Cin+c))*HW + p]*wl[c];
  out[((size_t)(b*Cout+co))*HW + p] = acc;
}

// ---------- criss-cross energies + softmax ----------
__global__ __launch_bounds__(128) void k_cc_att(
    float* __restrict__ att, const float* __restrict__ q, const float* __restrict__ k)
{
  __shared__ float qv[8];
  __shared__ float ev[128];
  int j = threadIdx.x; int w = blockIdx.x; int h = blockIdx.y; int b = blockIdx.z;
  if(j < 8) qv[j] = q[((size_t)(b*8+j))*HW + h*WD + w];
  __syncthreads();
  float e = 0.f;
  if(j < 64){
    #pragma unroll
    for(int c=0;c<8;c++) e += qv[c]*k[((size_t)(b*8+c))*HW + j*WD + w];
    if(j == h) e += NEGV;
  } else {
    int jj = j - 64;
    #pragma unroll
    for(int c=0;c<8;c++) e += qv[c]*k[((size_t)(b*8+c))*HW + h*WD + jj];
  }
  ev[j] = e;
  __syncthreads();
  for(int s=64; s>0; s>>=1){ if(j<s) ev[j] = fmaxf(ev[j], ev[j+s]); __syncthreads(); }
  float m = ev[0];
  __syncthreads();
  float p = __expf(e - m);
  ev[j] = p;
  __syncthreads();
  for(int s=64; s>0; s>>=1){ if(j<s) ev[j] += ev[j+s]; __syncthreads(); }
  float inv = 1.0f/ev[0];
  att[(((size_t)(b*HT+h))*WD + w)*128 + j] = p*inv;
}

// ---------- criss-cross aggregation ----------
__global__ __launch_bounds__(64) void k_cc_agg(
    float* __restrict__ out, const float* __restrict__ v, const float* __restrict__ att,
    const float* __restrict__ x, vp gamma, size_t go, const int* dflag)
{
  __shared__ float al[128];
  int f = *dflag;
  int c = threadIdx.x; int h = blockIdx.x; int w = blockIdx.y; int b = blockIdx.z;
  const float* ar = att + (((size_t)(b*HT+h))*WD + w)*128;
  al[c] = ar[c]; al[c+64] = ar[c+64];
  __syncthreads();
  float g = ldf(gamma, go, f);
  const float* vb = v + ((size_t)(b*64+c))*HW;
  float acc = 0.f;
  #pragma unroll 4
  for(int j=0;j<64;j++) acc += vb[(size_t)j*WD + w]*al[j];
  const float* vr = vb + (size_t)h*WD;
  #pragma unroll 4
  for(int j=0;j<64;j++) acc += vr[j]*al[64+j];
  size_t idx = ((size_t)(b*64+c))*HW + (size_t)h*WD + w;
  out[idx] = g*acc + x[idx];
}

// ---------- token transpose ----------
__global__ void k_mk_tokens(float* __restrict__ mem_t, const float* __restrict__ memf)
{
  int c = threadIdx.x; int s = blockIdx.x; int b = blockIdx.y;
  mem_t[((size_t)(b*HW+s))*256 + c] = memf[((size_t)(b*256+c))*HW + s];
}

// ---------- fp32 GEMM (small M) ----------
__global__ __launch_bounds__(256) void k_gemm(
    float* __restrict__ Y, const float* __restrict__ X, vp W, size_t wo,
    vp bias, size_t bo, vp pos2, int M, int N, int K, int relu, const int* dflag)
{
  __shared__ float Xs[16][68];
  __shared__ float Ws[16][68];
  int f = *dflag;
  int tid = threadIdx.x;
  int bn = blockIdx.x*64, bm = blockIdx.y*64;
  int tx = tid & 15, ty = tid >> 4;
  int mload = tid >> 2;
  int k4 = (tid & 3) * 4;
  float acc[4][4] = {{0}};
  for(int k0=0; k0<K; k0+=16){
    float4 xv = make_float4(0.f,0.f,0.f,0.f);
    int gm = bm + mload;
    if(gm < M){
      xv = *(const float4*)(X + (size_t)gm*K + k0 + k4);
      if(pos2){
        int b = gm >> 12, s = gm & 4095;
        size_t pb = ((size_t)(b*256 + k0 + k4))*HW + s;
        xv.x += ldf(pos2, pb,      f);
        xv.y += ldf(pos2, pb+HW,   f);
        xv.z += ldf(pos2, pb+2*HW, f);
        xv.w += ldf(pos2, pb+3*HW, f);
      }
    }
    Xs[k4+0][mload] = xv.x; Xs[k4+1][mload] = xv.y;
    Xs[k4+2][mload] = xv.z; Xs[k4+3][mload] = xv.w;
    size_t wr = wo + (size_t)(bn + mload)*K + k0 + k4;
    Ws[k4+0][mload] = ldf(W, wr,   f); Ws[k4+1][mload] = ldf(W, wr+1, f);
    Ws[k4+2][mload] = ldf(W, wr+2, f); Ws[k4+3][mload] = ldf(W, wr+3, f);
    __syncthreads();
    #pragma unroll
    for(int kk=0; kk<16; kk++){
      float a0=Xs[kk][ty*4+0], a1=Xs[kk][ty*4+1], a2=Xs[kk][ty*4+2], a3=Xs[kk][ty*4+3];
      float b0=Ws[kk][tx*4+0], b1=Ws[kk][tx*4+1], b2=Ws[kk][tx*4+2], b3=Ws[kk][tx*4+3];
      acc[0][0]+=a0*b0; acc[0][1]+=a0*b1; acc[0][2]+=a0*b2; acc[0][3]+=a0*b3;
      acc[1][0]+=a1*b0; acc[1][1]+=a1*b1; acc[1][2]+=a1*b2; acc[1][3]+=a1*b3;
      acc[2][0]+=a2*b0; acc[2][1]+=a2*b1; acc[2][2]+=a2*b2; acc[2][3]+=a2*b3;
      acc[3][0]+=a3*b0; acc[3][1]+=a3*b1; acc[3][2]+=a3*b2; acc[3][3]+=a3*b3;
    }
    __syncthreads();
  }
  #pragma unroll
  for(int i=0;i<4;i++){
    int m = bm + ty*4 + i;
    if(m >= M) continue;
    #pragma unroll
    for(int j=0;j<4;j++){
      int n = bn + tx*4 + j;
      float vv = acc[i][j] + (bias ? ldf(bias, bo + n, f) : 0.f);
      if(relu) vv = fmaxf(vv, 0.f);
      Y[(size_t)m*N + n] = vv;
    }
  }
}

// ---------- self-attention (fp32 K/V, small S) ----------
__global__ __launch_bounds__(64) void k_attn(
    float* __restrict__ out, const float* __restrict__ q,
    const float* __restrict__ k, const float* __restrict__ v,
    int B, int S, size_t bstride, size_t sstride, float scale)
{
  int lane = threadIdx.x;
  int l = blockIdx.x, h = blockIdx.y, b = blockIdx.z;
  const float4* qp = (const float4*)(q + ((size_t)(l*B+b))*256 + h*32);
  float4 qr[8];
  #pragma unroll
  for(int d=0; d<8; d++) qr[d] = qp[d];
  float m = -1e30f, lsum = 0.f;
  float acc[32];
  #pragma unroll
  for(int d=0; d<32; d++) acc[d] = 0.f;
  for(int s=lane; s<S; s+=64){
    const float4* kp = (const float4*)(k + b*bstride + (size_t)s*sstride + h*32);
    const float4* vp2 = (const float4*)(v + b*bstride + (size_t)s*sstride + h*32);
    float e = 0.f;
    #pragma unroll
    for(int d=0; d<8; d++){
      float4 kv = kp[d];
      e += qr[d].x*kv.x + qr[d].y*kv.y + qr[d].z*kv.z + qr[d].w*kv.w;
    }
    e *= scale;
    float nm = fmaxf(m, e);
    float ff = __expf(m - nm);
    float p = __expf(e - nm);
    lsum = lsum*ff + p;
    #pragma unroll
    for(int d=0; d<8; d++){
      float4 vv = vp2[d];
      acc[4*d+0] = acc[4*d+0]*ff + p*vv.x;
      acc[4*d+1] = acc[4*d+1]*ff + p*vv.y;
      acc[4*d+2] = acc[4*d+2]*ff + p*vv.z;
      acc[4*d+3] = acc[4*d+3]*ff + p*vv.w;
    }
    m = nm;
  }
  #pragma unroll
  for(int off=32; off>0; off>>=1){
    float om = __shfl_xor(m, off);
    float ol = __shfl_xor(lsum, off);
    float nm = fmaxf(m, om);
    float fa = __expf(m - nm), fb = __expf(om - nm);
    lsum = lsum*fa + ol*fb;
    #pragma unroll
    for(int d=0; d<32; d++){
      float oa = __shfl_xor(acc[d], off);
      acc[d] = acc[d]*fa + oa*fb;
    }
    m = nm;
  }
  if(lane == 0){
    float inv = 1.0f/lsum;
    float* op = out + ((size_t)(l*B+b))*256 + h*32;
    #pragma unroll
    for(int d=0; d<32; d++) op[d] = acc[d]*inv;
  }
}

// ---------- cross-attention: bf16 K/V, coalesced rows, 4 queries/block ----------
// grid (25, 8, 4), block 256 = 4 waves = 32 groups of 8 lanes.
// Group G handles s = G + 32*i. 8 lanes of a group each own d-slice (lane&7)*4.
__global__ __launch_bounds__(256) void k_attn_x(
    float* __restrict__ out, const float* __restrict__ q,
    const __hip_bfloat16* __restrict__ k, const __hip_bfloat16* __restrict__ v,
    float scale)
{
  __shared__ float red[4][4][34];   // [wave][j][ m, lsum, acc32 ]
  const int tid = threadIdx.x, lane = tid & 63, wv = tid >> 6;
  const int dl = lane & 7;
  const int G = wv*8 + (lane >> 3);
  const int l0 = blockIdx.x*4, h = blockIdx.y, b = blockIdx.z;

  float4 qr[4];
  #pragma unroll
  for(int j=0; j<4; j++)
    qr[j] = *(const float4*)(q + ((size_t)((l0+j)*4 + b))*256 + h*32 + dl*4);

  const unsigned short* kb = (const unsigned short*)k + ((size_t)b*HW)*256 + h*32 + dl*4;
  const unsigned short* vb = (const unsigned short*)v + ((size_t)b*HW)*256 + h*32 + dl*4;

  float m[4], ls[4]; f32x4 acc[4];
  #pragma unroll
  for(int j=0; j<4; j++){ m[j] = -1e30f; ls[j] = 0.f; acc[j] = (f32x4){0.f,0.f,0.f,0.f}; }

  for(int s=G; s<HW; s+=32){
    ushort4 k4 = *(const ushort4*)(kb + (size_t)s*256);
    ushort4 v4 = *(const ushort4*)(vb + (size_t)s*256);
    float kx = u2f(k4.x), ky = u2f(k4.y), kz = u2f(k4.z), kw = u2f(k4.w);
    float vx = u2f(v4.x), vy = u2f(v4.y), vz = u2f(v4.z), vw = u2f(v4.w);
    #pragma unroll
    for(int j=0; j<4; j++){
      float e = qr[j].x*kx + qr[j].y*ky + qr[j].z*kz + qr[j].w*kw;
      e += __shfl_xor(e, 1); e += __shfl_xor(e, 2); e += __shfl_xor(e, 4);
      e *= scale;
      float nm = fmaxf(m[j], e);
      float ff = __expf(m[j] - nm);
      float p  = __expf(e - nm);
      ls[j] = ls[j]*ff + p;
      acc[j][0] = acc[j][0]*ff + p*vx;
      acc[j][1] = acc[j][1]*ff + p*vy;
      acc[j][2] = acc[j][2]*ff + p*vz;
      acc[j][3] = acc[j][3]*ff + p*vw;
      m[j] = nm;
    }
  }
  // merge 8 groups within the wave
  #pragma unroll
  for(int off=8; off<64; off<<=1){
    #pragma unroll
    for(int j=0; j<4; j++){
      float om = __shfl_xor(m[j], off);
      float ol = __shfl_xor(ls[j], off);
      f32x4 oa;
      oa[0] = __shfl_xor(acc[j][0], off); oa[1] = __shfl_xor(acc[j][1], off);
      oa[2] = __shfl_xor(acc[j][2], off); oa[3] = __shfl_xor(acc[j][3], off);
      float nm = fmaxf(m[j], om);
      float fa = __expf(m[j] - nm), fb = __expf(om - nm);
      ls[j] = ls[j]*fa + ol*fb;
      #pragma unroll
      for(int t=0; t<4; t++) acc[j][t] = acc[j][t]*fa + oa[t]*fb;
      m[j] = nm;
    }
  }
  // cross-wave merge via LDS
  if(lane < 8){
    #pragma unroll
    for(int j=0; j<4; j++){
      if(lane == 0){ red[wv][j][0] = m[j]; red[wv][j][1] = ls[j]; }
      #pragma unroll
      for(int t=0; t<4; t++) red[wv][j][2 + dl*4 + t] = acc[j][t];
    }
  }
  __syncthreads();
  if(wv == 0 && lane < 8){
    #pragma unroll
    for(int j=0; j<4; j++){
      float M = red[0][j][0], L = red[0][j][1];
      f32x4 A;
      #pragma unroll
      for(int t=0; t<4; t++) A[t] = red[0][j][2 + dl*4 + t];
      #pragma unroll
      for(int w2=1; w2<4; w2++){
        float om = red[w2][j][0], ol = red[w2][j][1];
        float nm = fmaxf(M, om);
        float fa = __expf(M - nm), fb = __expf(om - nm);
        L = L*fa + ol*fb;
        #pragma unroll
        for(int t=0; t<4; t++) A[t] = A[t]*fa + red[w2][j][2 + dl*4 + t]*fb;
        M = nm;
      }
      float inv = 1.0f/L;
      float4 o4 = make_float4(A[0]*inv, A[1]*inv, A[2]*inv, A[3]*inv);
      *(float4*)(out + ((size_t)((l0+j)*4 + b))*256 + h*32 + dl*4) = o4;
    }
  }
}

// ---------- LayerNorm over C=256 ----------
__global__ __launch_bounds__(256) void k_ln(
    float* dst, const float* x, const float* t2, vp g, vp bb, size_t go, const int* dflag)
{
  __shared__ float red[256];
  int f = *dflag;
  int c = threadIdx.x; int tok = blockIdx.x;
  float v = x[(size_t)tok*256 + c];
  if(t2) v += t2[(size_t)tok*256 + c];
  red[c] = v; __syncthreads();
  for(int s=128; s>0; s>>=1){ if(c<s) red[c] += red[c+s]; __syncthreads(); }
  float mu = red[0]*(1.f/256.f);
  __syncthreads();
  float dv = v - mu;
  red[c] = dv*dv; __syncthreads();
  for(int s=128; s>0; s>>=1){ if(c<s) red[c] += red[c+s]; __syncthreads(); }
  float var = red[0]*(1.f/256.f);
  float r = rsqrtf(var + 1e-5f);
  dst[(size_t)tok*256 + c] = dv*r*ldf(g, go+c, f) + ldf(bb, go+c, f);
}

__global__ void k_addqe(float* dst, const float* outq, vp qe, const int* dflag){
  int f = *dflag;
  int c = threadIdx.x; int tok = blockIdx.x; int l = tok >> 2;
  dst[(size_t)tok*256 + c] = outq[(size_t)tok*256 + c] + ldf(qe, (size_t)l*256 + c, f);
}

__global__ void k_write_hs(void* out, const float* lnout, const int* dflag){
  int f = *dflag;
  int c = threadIdx.x; int tok = blockIdx.x; int l = tok >> 2; int b = tok & 3;
  float v = lnout[(size_t)tok*256 + c];
  size_t o = ((size_t)(b*100+l))*256 + c;
  if(f) ((float*)out)[o] = v;
  else  ((__hip_bfloat16*)out)[o] = __float2bfloat16(v);
}

extern "C" void kernel_launch(void* const* d_in, const int* in_sizes, int n_in,
                              void* d_out, int out_size, void* d_ws, size_t ws_size,
                              hipStream_t stream) {
  vp src       = d_in[0];
  vp query_emb = d_in[2];
  vp pos       = d_in[3];
  vp conva_w   = d_in[4];
  vp q_w = d_in[5];  vp q_b = d_in[6];
  vp k_w = d_in[7];  vp k_b = d_in[8];
  vp v_w = d_in[9];  vp v_b = d_in[10];
  vp gamma = d_in[11];
  vp convb_w = d_in[12];
  vp bneck_w = d_in[13];
  vp sa_in_w = d_in[14];  vp sa_in_b = d_in[15];
  vp sa_out_w = d_in[16]; vp sa_out_b = d_in[17];
  vp ca_in_w = d_in[18];  vp ca_in_b = d_in[19];
  vp ca_out_w = d_in[20]; vp ca_out_b = d_in[21];
  vp lin1_w = d_in[22];   vp lin1_b = d_in[23];
  vp lin2_w = d_in[24];   vp lin2_b = d_in[25];
  vp n1g = d_in[26]; vp n1b = d_in[27];
  vp n2g = d_in[28]; vp n2b = d_in[29];
  vp n3g = d_in[30]; vp n3b = d_in[31];
  vp normg = d_in[32]; vp normb = d_in[33];

  const size_t MEG = 1048576;
  float* ws   = (float*)d_ws;
  float* memf  = ws;                    // 4M floats
  float* xi    = ws + 4*MEG;            // 4M
  float* y64a  = ws + 8*MEG;            // 1M
  float* y64b  = ws + 9*MEG;            // 1M
  float* vb_   = ws + 10*MEG;           // 1M
  float* qb_   = ws + 11*MEG;           // 128K
  float* kb_   = ws + 11*MEG + 131072;  // 128K
  float* attb  = ws + 11*MEG + 262144;  // 2M (ends 13.25M)
  float* y256  = ws + 9*MEG;            // 4M (overlaps dead cc buffers)
  float* mem_t = xi;                    // decoder
  __hip_bfloat16* kproj = (__hip_bfloat16*)memf;        // decoder, bf16 (8 MB)
  __hip_bfloat16* vproj = (__hip_bfloat16*)(ws + 8*MEG);// decoder, bf16 (8 MB)
  float* sm    = ws + 13*MEG + 262144;
  float* outq   = sm;
  float* xq     = sm + 102400;
  float* qproj  = sm + 204800;
  float* kself  = sm + 307200;
  float* vself  = sm + 409600;
  float* attout = sm + 512000;
  float* t2     = sm + 614400;
  float* ffn1   = sm + 716800;          // 819200
  float* lnout  = sm + 1536000;         // ends 1,638,400 -> ws offset 15,532,032
  unsigned short* Wp = (unsigned short*)(ws + 15532032);
  int*   dflag  = (int*)(ws + 15532032 + 589824);

  const int NFULL = 4194304;
  const float scale = 0.17677669529663687f;

  k_detect<<<1, 256, 0, stream>>>(dflag, (const unsigned short*)src);
  k_cvt<<<(NFULL+255)/256, 256, 0, stream>>>(memf, src, NFULL, dflag);

  // ------------- encoder -------------
  for(int i=0; i<6; i++){
    k_addpos<<<(NFULL+255)/256, 256, 0, stream>>>(xi, memf, pos, NFULL, dflag);
    k_repack<<<72, 256, 0, stream>>>(Wp, conva_w, (size_t)i*147456, 256, 64, dflag);
    k_conv3x3_mfma<<<dim3(64,1,4), 256, 0, stream>>>(y64a, xi, nullptr, Wp, 256, 0, 64, 1);
    for(int pass=0; pass<2; pass++){
      const float* cx = pass ? y64b : y64a;
      float* cy       = pass ? y64a : y64b;
      k_conv1x1<<<dim3(64,8,4),  64, 0, stream>>>(qb_, cx, q_w, (size_t)i*512,  q_b, (size_t)i*8,  64, 8,  dflag);
      k_conv1x1<<<dim3(64,8,4),  64, 0, stream>>>(kb_, cx, k_w, (size_t)i*512,  k_b, (size_t)i*8,  64, 8,  dflag);
      k_conv1x1<<<dim3(64,64,4), 64, 0, stream>>>(vb_, cx, v_w, (size_t)i*4096, v_b, (size_t)i*64, 64, 64, dflag);
      k_cc_att<<<dim3(64,64,4), 128, 0, stream>>>(attb, qb_, kb_);
      k_cc_agg<<<dim3(64,64,4), 64, 0, stream>>>(cy, vb_, attb, cx, gamma, (size_t)i, dflag);
    }
    k_repack<<<72, 256, 0, stream>>>(Wp, convb_w, (size_t)i*147456, 64, 256, dflag);
    k_conv3x3_mfma<<<dim3(64,4,4), 256, 0, stream>>>(y256, y64a, nullptr, Wp, 64, 0, 256, 1);
    k_repack<<<576, 256, 0, stream>>>(Wp, bneck_w, (size_t)i*1179648, 512, 256, dflag);
    k_conv3x3_mfma<<<dim3(64,4,4), 256, 0, stream>>>(memf, xi, y256, Wp, 256, 256, 256, 0);
  }

  // ------------- decoder prep (before kproj overwrites memf) -------------
  k_mk_tokens<<<dim3(4096,4), 256, 0, stream>>>(mem_t, memf);
  k_write_mem<<<(NFULL+255)/256, 256, 0, stream>>>(d_out, memf, NFULL, dflag);
  k_zero<<<400, 256, 0, stream>>>(outq, 102400);

  // ------------- decoder layers -------------
  for(int i=0; i<6; i++){
    size_t iw = (size_t)i*196608, ib = (size_t)i*768;
    size_t ow = (size_t)i*65536,  ob = (size_t)i*256;
    // self-attention
    k_addqe<<<400, 256, 0, stream>>>(xq, outq, query_emb, dflag);
    k_gemm<<<dim3(4,7), 256, 0, stream>>>(qproj, xq,   sa_in_w, iw,        sa_in_b, ib,     nullptr, 400, 256, 256, 0, dflag);
    k_gemm<<<dim3(4,7), 256, 0, stream>>>(kself, xq,   sa_in_w, iw+65536,  sa_in_b, ib+256, nullptr, 400, 256, 256, 0, dflag);
    k_gemm<<<dim3(4,7), 256, 0, stream>>>(vself, outq, sa_in_w, iw+131072, sa_in_b, ib+512, nullptr, 400, 256, 256, 0, dflag);
    k_attn<<<dim3(100,8,4), 64, 0, stream>>>(attout, qproj, kself, vself,
        4, 100, (size_t)256, (size_t)1024, scale);
    k_gemm<<<dim3(4,7), 256, 0, stream>>>(t2, attout, sa_out_w, ow, sa_out_b, ob, nullptr, 400, 256, 256, 0, dflag);
    k_ln<<<400, 256, 0, stream>>>(outq, outq, t2, n1g, n1b, ob, dflag);
    // cross-attention
    k_addqe<<<400, 256, 0, stream>>>(xq, outq, query_emb, dflag);
    k_gemm<<<dim3(4,7), 256, 0, stream>>>(qproj, xq, ca_in_w, iw, ca_in_b, ib, nullptr, 400, 256, 256, 0, dflag);
    k_gemm_mfma<<<dim3(4,256), 256, 0, stream>>>(kproj, mem_t, ca_in_w, iw+65536,  ca_in_b, ib+256, pos,     16384, 256, 256, dflag);
    k_gemm_mfma<<<dim3(4,256), 256, 0, stream>>>(vproj, mem_t, ca_in_w, iw+131072, ca_in_b, ib+512, nullptr, 16384, 256, 256, dflag);
    k_attn_x<<<dim3(25,8,4), 256, 0, stream>>>(attout, qproj, kproj, vproj, scale);
    k_gemm<<<dim3(4,7), 256, 0, stream>>>(t2, attout, ca_out_w, ow, ca_out_b, ob, nullptr, 400, 256, 256, 0, dflag);
    k_ln<<<400, 256, 0, stream>>>(outq, outq, t2, n2g, n2b, ob, dflag);
    // FFN
    k_gemm<<<dim3(32,7), 256, 0, stream>>>(ffn1, outq, lin1_w, (size_t)i*524288, lin1_b, (size_t)i*2048, nullptr, 400, 2048, 256, 1, dflag);
    k_gemm<<<dim3(4,7),  256, 0, stream>>>(t2,   ffn1, lin2_w, (size_t)i*524288, lin2_b, ob,             nullptr, 400, 256, 2048, 0, dflag);
    k_ln<<<400, 256, 0, stream>>>(outq, outq, t2, n3g, n3b, ob, dflag);
  }

  k_ln<<<400, 256, 0, stream>>>(lnout, outq, nullptr, normg, normb, (size_t)0, dflag);
  k_write_hs<<<400, 256, 0, stream>>>(d_out, lnout, dflag);
}

// Round 7
// 5308.485 us; speedup vs baseline: 5.1167x; 1.5705x over previous
//
#include <hip/hip_runtime.h>
#include <hip/hip_bf16.h>

#define HW 4096
#define WD 64
#define HT 64
#define NEGV -1000000000.0f

typedef const void* vp;
typedef __attribute__((ext_vector_type(8))) short bf16x8;
typedef __attribute__((ext_vector_type(8))) unsigned short ushort8;
typedef __attribute__((ext_vector_type(4))) float f32x4;

__device__ __forceinline__ float b2f(__hip_bfloat16 v){ return __bfloat162float(v); }
__device__ __forceinline__ float ldf(vp p, size_t i, int f){
  return f ? ((const float*)p)[i] : b2f(((const __hip_bfloat16*)p)[i]);
}
__device__ __forceinline__ unsigned short f2b(float x){
  __hip_bfloat16 h = __float2bfloat16(x);
  return *reinterpret_cast<unsigned short*>(&h);
}
__device__ __forceinline__ float u2f(unsigned short u){
  union { unsigned int i; float f; } x; x.i = ((unsigned int)u) << 16; return x.f;
}

// ---------- dtype detector ----------
__global__ void k_detect(int* flag, const unsigned short* p){
  __shared__ int cnt;
  if(threadIdx.x==0) cnt=0;
  __syncthreads();
  int c=0;
  for(int i=threadIdx.x; i<512; i+=256){
    int e = (p[i]>>7)&0xFF;
    if(e>150 || e<100) c++;
  }
  atomicAdd(&cnt, c);
  __syncthreads();
  if(threadIdx.x==0) *flag = (cnt>32) ? 1 : 0;  // 1 = fp32 inputs
}

// ---------- elementwise ----------
__global__ void k_cvt(float* dst, vp src, int n, const int* dflag){
  int f = *dflag;
  int i = blockIdx.x*256 + threadIdx.x;
  if(i<n) dst[i] = ldf(src, i, f);
}

__global__ void k_addpos(float* xi, const float* memf, vp pos, int n, const int* dflag){
  int f = *dflag;
  int i = blockIdx.x*256 + threadIdx.x;
  if(i<n) xi[i] = memf[i] + ldf(pos, i, f);
}

__global__ void k_zero(float* p, int n){
  int i = blockIdx.x*256 + threadIdx.x;
  if(i<n) p[i] = 0.f;
}

__global__ void k_write_mem(void* out, const float* src, int n, const int* dflag){
  int f = *dflag;
  int i = blockIdx.x*256 + threadIdx.x;
  if(i<n){
    if(f) ((float*)out)[102400 + i] = src[i];
    else  ((__hip_bfloat16*)out)[102400 + i] = __float2bfloat16(src[i]);
  }
}

// ---------- conv weight repack into A-fragment order ----------
__global__ void k_repack(unsigned short* Wp, vp w, size_t wo, int Cin, int Cout, const int* dflag){
  int f = *dflag;
  int slab = blockIdx.x;
  int tap = slab % 9; int t2 = slab / 9;
  int nch = Cin >> 5; int ch = t2 % nch; int cotile = t2 / nch;
  for(int e=threadIdx.x; e<2048; e+=256){
    int col = e >> 5, ciL = e & 31;
    size_t co = cotile*64 + col, ci = ch*32 + ciL;
    float v = ldf(w, wo + (co*Cin + ci)*9 + tap, f);
    Wp[(size_t)slab*2048 + e] = f2b(v);
  }
}

// ---------- 3x3 conv via MFMA implicit GEMM (repacked weights) ----------
__global__ __launch_bounds__(256) void k_conv3x3_mfma(
    float* __restrict__ out, const float* __restrict__ in1, const float* __restrict__ in2,
    const unsigned short* __restrict__ Wp, int Cin1, int Cin2, int Cout, int relu)
{
  __shared__ __attribute__((aligned(16))) unsigned short Xs[3*66*40];
  const int tid  = threadIdx.x;
  const int lane = tid & 63;
  const int wv   = tid >> 6;
  const int quad = lane >> 4;
  const int l16  = lane & 15;
  const int h    = blockIdx.x;
  const int cotile = blockIdx.y;
  const int b    = blockIdx.z;
  const int Cin  = Cin1 + Cin2;
  const int nch  = Cin >> 5;

  if(tid < 96){
    int kh = tid>>5, ci = tid&31;
    Xs[(kh*66 + 0)*40 + ci]  = 0;
    Xs[(kh*66 + 65)*40 + ci] = 0;
  }

  f32x4 acc[4];
  #pragma unroll
  for(int nt=0; nt<4; nt++) acc[nt] = (f32x4){0.f,0.f,0.f,0.f};

  const unsigned short* wlane = Wp + ((size_t)cotile*nch)*9*2048 + (wv*16+l16)*32 + quad*8;

  for(int ch=0; ch<nch; ch++){
    __syncthreads();
    #pragma unroll
    for(int it=0; it<6; it++){
      int t   = it*256 + tid;
      int kh  = t >> 9;
      int rem = t & 511;
      int ci  = rem >> 4;
      int w4  = (rem & 15) << 2;
      int r   = h + kh - 1;
      float4 xv = make_float4(0.f,0.f,0.f,0.f);
      int cg = ch*32 + ci;
      if(r >= 0 && r < HT){
        const float* srcp = (cg < Cin1) ? in1 + ((size_t)(b*Cin1+cg))*HW
                                        : in2 + ((size_t)(b*Cin2+(cg-Cin1)))*HW;
        xv = *(const float4*)(srcp + r*WD + w4);
      }
      int base = (kh*66 + w4 + 1)*40 + ci;
      Xs[base]      = f2b(xv.x);
      Xs[base+40]   = f2b(xv.y);
      Xs[base+80]   = f2b(xv.z);
      Xs[base+120]  = f2b(xv.w);
    }
    __syncthreads();
    const unsigned short* wch = wlane + (size_t)ch*9*2048;
    #pragma unroll
    for(int tap=0; tap<9; tap++){
      const int kh = tap/3, kw = tap%3;
      bf16x8 af = *(const bf16x8*)(wch + tap*2048);
      #pragma unroll
      for(int nt=0; nt<4; nt++){
        bf16x8 bfr = *(const bf16x8*)&Xs[(kh*66 + nt*16 + l16 + kw)*40 + quad*8];
        acc[nt] = __builtin_amdgcn_mfma_f32_16x16x32_bf16(af, bfr, acc[nt], 0, 0, 0);
      }
    }
  }
  #pragma unroll
  for(int nt=0; nt<4; nt++){
    #pragma unroll
    for(int r=0; r<4; r++){
      float vv = acc[nt][r];
      if(relu) vv = fmaxf(vv, 0.f);
      out[((size_t)(b*Cout + cotile*64 + wv*16 + quad*4 + r))*HW + h*WD + nt*16 + l16] = vv;
    }
  }
}

// ---------- MFMA GEMM with bf16 output ----------
__global__ __launch_bounds__(256) void k_gemm_mfma(
    __hip_bfloat16* __restrict__ Y, const float* __restrict__ X, vp W, size_t wo,
    vp bias, size_t bo, vp pos2, int M, int N, int K, const int* dflag)
{
  __shared__ __attribute__((aligned(16))) unsigned short Xs[64*40];
  __shared__ __attribute__((aligned(16))) unsigned short Ws[64*40];
  const int f = *dflag;
  const int tid = threadIdx.x;
  const int bn = blockIdx.x*64, bm = blockIdx.y*64;
  const int lane = tid & 63, wv = tid >> 6, quad = lane >> 4, l16 = lane & 15;
  const int row = tid >> 2, kq = (tid & 3) * 8;

  f32x4 acc[4];
  #pragma unroll
  for(int mt=0; mt<4; mt++) acc[mt] = (f32x4){0.f,0.f,0.f,0.f};

  for(int k0=0; k0<K; k0+=32){
    __syncthreads();
    {
      int gm = bm + row;
      const float* xp = X + (size_t)gm*K + k0 + kq;
      float4 xa = *(const float4*)xp;
      float4 xb = *(const float4*)(xp+4);
      if(pos2){
        int b = gm >> 12, s = gm & 4095;
        size_t pb = ((size_t)(b*256 + k0 + kq))*HW + s;
        xa.x += ldf(pos2, pb,      f); xa.y += ldf(pos2, pb+HW,   f);
        xa.z += ldf(pos2, pb+2*HW, f); xa.w += ldf(pos2, pb+3*HW, f);
        xb.x += ldf(pos2, pb+4*HW, f); xb.y += ldf(pos2, pb+5*HW, f);
        xb.z += ldf(pos2, pb+6*HW, f); xb.w += ldf(pos2, pb+7*HW, f);
      }
      ushort8 xo;
      xo[0]=f2b(xa.x); xo[1]=f2b(xa.y); xo[2]=f2b(xa.z); xo[3]=f2b(xa.w);
      xo[4]=f2b(xb.x); xo[5]=f2b(xb.y); xo[6]=f2b(xb.z); xo[7]=f2b(xb.w);
      *(ushort8*)&Xs[row*40 + kq] = xo;
    }
    {
      size_t wr = wo + (size_t)(bn + row)*K + k0 + kq;
      ushort8 wo8;
      if(f){
        const float* wp2 = (const float*)W + wr;
        float4 wa = *(const float4*)wp2;
        float4 wb = *(const float4*)(wp2+4);
        wo8[0]=f2b(wa.x); wo8[1]=f2b(wa.y); wo8[2]=f2b(wa.z); wo8[3]=f2b(wa.w);
        wo8[4]=f2b(wb.x); wo8[5]=f2b(wb.y); wo8[6]=f2b(wb.z); wo8[7]=f2b(wb.w);
      } else {
        wo8 = *(const ushort8*)((const unsigned short*)W + wr);
      }
      *(ushort8*)&Ws[row*40 + kq] = wo8;
    }
    __syncthreads();
    bf16x8 bfr = *(const bf16x8*)&Ws[(wv*16 + l16)*40 + quad*8];
    #pragma unroll
    for(int mt=0; mt<4; mt++){
      bf16x8 af = *(const bf16x8*)&Xs[(mt*16 + l16)*40 + quad*8];
      acc[mt] = __builtin_amdgcn_mfma_f32_16x16x32_bf16(af, bfr, acc[mt], 0, 0, 0);
    }
  }
  const int n = bn + wv*16 + l16;
  const float bv = ldf(bias, bo + n, f);
  #pragma unroll
  for(int mt=0; mt<4; mt++){
    #pragma unroll
    for(int r=0; r<4; r++){
      int m = bm + mt*16 + quad*4 + r;
      Y[(size_t)m*N + n] = __float2bfloat16(acc[mt][r] + bv);
    }
  }
}

// ---------- 1x1 conv with bias (Cin<=64) ----------
__global__ __launch_bounds__(64) void k_conv1x1(
    float* __restrict__ out, const float* __restrict__ in, vp w, size_t wo,
    vp bias, size_t bo, int Cin, int Cout, const int* dflag)
{
  __shared__ float wl[64];
  int f = *dflag;
  int tid = threadIdx.x; int co = blockIdx.y; int b = blockIdx.z;
  int p = blockIdx.x*64 + tid;
  for(int i=tid; i<Cin; i+=64) wl[i] = ldf(w, wo + (size_t)co*Cin + i, f);
  __syncthreads();
  float acc = ldf(bias, bo + co, f);
  for(int c=0; c<Cin; c++) acc += in[((size_t)(b*Cin+c))*HW + p]*wl[c];
  out[((size_t)(b*Cout+co))*HW + p] = acc;
}

// ---------- fused criss-cross: energies + softmax + aggregation ----------
// grid (HT, B), block 256 (4 waves). Lanes = w (coalesced everywhere).
// out[b,c,h,w] = gamma*(sum_j V[c,j,w]*softH + sum_j V[c,h,j]*softW) + x[b,c,h,w]
__global__ __launch_bounds__(256) void k_cc_fused(
    float* __restrict__ out, const float* __restrict__ v,
    const float* __restrict__ q, const float* __restrict__ k,
    const float* __restrict__ x, vp gamma, size_t go, const int* dflag)
{
  __shared__ float E[64*129];   // [w][j], pad 129 -> bank (w+j)%32, 2-way free
  __shared__ float Vh[64*65];   // [c][j] = V[b,c,h,j]
  __shared__ float qs[8*64];    // [c][w]
  __shared__ float kh[8*64];    // [c][j]
  __shared__ float red[4*64];
  __shared__ float Mw[64], Sw[64];
  const int tid = threadIdx.x, lane = tid & 63, wv = tid >> 6;
  const int h = blockIdx.x, b = blockIdx.y;
  const int f = *dflag;

  // stage q row, k row, V rows at h (all coalesced)
  for(int cc=wv; cc<8; cc+=4){
    qs[cc*64+lane] = q[((size_t)(b*8+cc))*HW + h*WD + lane];
    kh[cc*64+lane] = k[((size_t)(b*8+cc))*HW + h*WD + lane];
  }
  for(int cc=wv; cc<64; cc+=4)
    Vh[cc*65+lane] = v[((size_t)(b*64+cc))*HW + h*WD + lane];
  __syncthreads();

  // energies: wave wv covers j in [wv*32, wv*32+32)
  {
    const int w = lane;
    for(int jt=0; jt<32; jt++){
      int j = wv*32 + jt;
      float e = 0.f;
      if(j < 64){
        const float* kcol = k + ((size_t)(b*8))*HW + (size_t)j*WD + w;
        #pragma unroll
        for(int c=0;c<8;c++) e += qs[c*64+w]*kcol[(size_t)c*HW];
        if(j == h) e += NEGV;
      } else {
        int jj = j - 64;
        #pragma unroll
        for(int c=0;c<8;c++) e += qs[c*64+w]*kh[c*64+jj];
      }
      E[w*129 + j] = e;
    }
  }
  __syncthreads();
  // softmax: partial max per (w, wave)
  {
    const int w = lane;
    float mx = -1e30f;
    for(int jt=0; jt<32; jt++) mx = fmaxf(mx, E[w*129 + wv*32 + jt]);
    red[wv*64+w] = mx;
  }
  __syncthreads();
  if(wv==0){
    int w = lane;
    Mw[w] = fmaxf(fmaxf(red[w], red[64+w]), fmaxf(red[128+w], red[192+w]));
  }
  __syncthreads();
  {
    const int w = lane;
    float mx = Mw[w], s = 0.f;
    for(int jt=0; jt<32; jt++){
      int j = wv*32 + jt;
      float p = __expf(E[w*129+j] - mx);
      E[w*129+j] = p;
      s += p;
    }
    red[wv*64+w] = s;
  }
  __syncthreads();
  if(wv==0){
    int w = lane;
    Sw[w] = 1.0f/(red[w]+red[64+w]+red[128+w]+red[192+w]);
  }
  __syncthreads();
  // aggregation: wave wv owns channels [wv*16, +16), lane = w
  {
    const int w = lane;
    const int c0 = wv*16;
    float acc[16];
    #pragma unroll
    for(int i=0;i<16;i++) acc[i] = 0.f;
    // vertical: V[b,c,j,w] — coalesced 256B row per (c,j)
    const float* vbase = v + ((size_t)(b*64 + c0))*HW + w;
    for(int j=0;j<64;j++){
      float p = E[w*129 + j];
      const float* vcol = vbase + (size_t)j*WD;
      #pragma unroll
      for(int i=0;i<16;i++) acc[i] += vcol[(size_t)i*HW]*p;
    }
    // horizontal: Vh[c][j] (LDS broadcast)
    for(int j=0;j<64;j++){
      float p = E[w*129 + 64 + j];
      #pragma unroll
      for(int i=0;i<16;i++) acc[i] += Vh[(c0+i)*65 + j]*p;
    }
    float g = ldf(gamma, go, f);
    float inv = Sw[w];
    #pragma unroll
    for(int i=0;i<16;i++){
      size_t idx = ((size_t)(b*64 + c0 + i))*HW + (size_t)h*WD + w;
      out[idx] = g*(acc[i]*inv) + x[idx];
    }
  }
}

// ---------- token transpose ----------
__global__ void k_mk_tokens(float* __restrict__ mem_t, const float* __restrict__ memf)
{
  int c = threadIdx.x; int s = blockIdx.x; int b = blockIdx.y;
  mem_t[((size_t)(b*HW+s))*256 + c] = memf[((size_t)(b*256+c))*HW + s];
}

// ---------- fp32 GEMM (small M) ----------
__global__ __launch_bounds__(256) void k_gemm(
    float* __restrict__ Y, const float* __restrict__ X, vp W, size_t wo,
    vp bias, size_t bo, vp pos2, int M, int N, int K, int relu, const int* dflag)
{
  __shared__ float Xs[16][68];
  __shared__ float Ws[16][68];
  int f = *dflag;
  int tid = threadIdx.x;
  int bn = blockIdx.x*64, bm = blockIdx.y*64;
  int tx = tid & 15, ty = tid >> 4;
  int mload = tid >> 2;
  int k4 = (tid & 3) * 4;
  float acc[4][4] = {{0}};
  for(int k0=0; k0<K; k0+=16){
    float4 xv = make_float4(0.f,0.f,0.f,0.f);
    int gm = bm + mload;
    if(gm < M){
      xv = *(const float4*)(X + (size_t)gm*K + k0 + k4);
      if(pos2){
        int b = gm >> 12, s = gm & 4095;
        size_t pb = ((size_t)(b*256 + k0 + k4))*HW + s;
        xv.x += ldf(pos2, pb,      f);
        xv.y += ldf(pos2, pb+HW,   f);
        xv.z += ldf(pos2, pb+2*HW, f);
        xv.w += ldf(pos2, pb+3*HW, f);
      }
    }
    Xs[k4+0][mload] = xv.x; Xs[k4+1][mload] = xv.y;
    Xs[k4+2][mload] = xv.z; Xs[k4+3][mload] = xv.w;
    size_t wr = wo + (size_t)(bn + mload)*K + k0 + k4;
    Ws[k4+0][mload] = ldf(W, wr,   f); Ws[k4+1][mload] = ldf(W, wr+1, f);
    Ws[k4+2][mload] = ldf(W, wr+2, f); Ws[k4+3][mload] = ldf(W, wr+3, f);
    __syncthreads();
    #pragma unroll
    for(int kk=0; kk<16; kk++){
      float a0=Xs[kk][ty*4+0], a1=Xs[kk][ty*4+1], a2=Xs[kk][ty*4+2], a3=Xs[kk][ty*4+3];
      float b0=Ws[kk][tx*4+0], b1=Ws[kk][tx*4+1], b2=Ws[kk][tx*4+2], b3=Ws[kk][tx*4+3];
      acc[0][0]+=a0*b0; acc[0][1]+=a0*b1; acc[0][2]+=a0*b2; acc[0][3]+=a0*b3;
      acc[1][0]+=a1*b0; acc[1][1]+=a1*b1; acc[1][2]+=a1*b2; acc[1][3]+=a1*b3;
      acc[2][0]+=a2*b0; acc[2][1]+=a2*b1; acc[2][2]+=a2*b2; acc[2][3]+=a2*b3;
      acc[3][0]+=a3*b0; acc[3][1]+=a3*b1; acc[3][2]+=a3*b2; acc[3][3]+=a3*b3;
    }
    __syncthreads();
  }
  #pragma unroll
  for(int i=0;i<4;i++){
    int m = bm + ty*4 + i;
    if(m >= M) continue;
    #pragma unroll
    for(int j=0;j<4;j++){
      int n = bn + tx*4 + j;
      float vv = acc[i][j] + (bias ? ldf(bias, bo + n, f) : 0.f);
      if(relu) vv = fmaxf(vv, 0.f);
      Y[(size_t)m*N + n] = vv;
    }
  }
}

// ---------- self-attention (fp32 K/V, small S) ----------
__global__ __launch_bounds__(64) void k_attn(
    float* __restrict__ out, const float* __restrict__ q,
    const float* __restrict__ k, const float* __restrict__ v,
    int B, int S, size_t bstride, size_t sstride, float scale)
{
  int lane = threadIdx.x;
  int l = blockIdx.x, h = blockIdx.y, b = blockIdx.z;
  const float4* qp = (const float4*)(q + ((size_t)(l*B+b))*256 + h*32);
  float4 qr[8];
  #pragma unroll
  for(int d=0; d<8; d++) qr[d] = qp[d];
  float m = -1e30f, lsum = 0.f;
  float acc[32];
  #pragma unroll
  for(int d=0; d<32; d++) acc[d] = 0.f;
  for(int s=lane; s<S; s+=64){
    const float4* kp = (const float4*)(k + b*bstride + (size_t)s*sstride + h*32);
    const float4* vp2 = (const float4*)(v + b*bstride + (size_t)s*sstride + h*32);
    float e = 0.f;
    #pragma unroll
    for(int d=0; d<8; d++){
      float4 kv = kp[d];
      e += qr[d].x*kv.x + qr[d].y*kv.y + qr[d].z*kv.z + qr[d].w*kv.w;
    }
    e *= scale;
    float nm = fmaxf(m, e);
    float ff = __expf(m - nm);
    float p = __expf(e - nm);
    lsum = lsum*ff + p;
    #pragma unroll
    for(int d=0; d<8; d++){
      float4 vv = vp2[d];
      acc[4*d+0] = acc[4*d+0]*ff + p*vv.x;
      acc[4*d+1] = acc[4*d+1]*ff + p*vv.y;
      acc[4*d+2] = acc[4*d+2]*ff + p*vv.z;
      acc[4*d+3] = acc[4*d+3]*ff + p*vv.w;
    }
    m = nm;
  }
  #pragma unroll
  for(int off=32; off>0; off>>=1){
    float om = __shfl_xor(m, off);
    float ol = __shfl_xor(lsum, off);
    float nm = fmaxf(m, om);
    float fa = __expf(m - nm), fb = __expf(om - nm);
    lsum = lsum*fa + ol*fb;
    #pragma unroll
    for(int d=0; d<32; d++){
      float oa = __shfl_xor(acc[d], off);
      acc[d] = acc[d]*fa + oa*fb;
    }
    m = nm;
  }
  if(lane == 0){
    float inv = 1.0f/lsum;
    float* op = out + ((size_t)(l*B+b))*256 + h*32;
    #pragma unroll
    for(int d=0; d<32; d++) op[d] = acc[d]*inv;
  }
}

// ---------- cross-attention: bf16 K/V, coalesced rows, 4 queries/block ----------
__global__ __launch_bounds__(256) void k_attn_x(
    float* __restrict__ out, const float* __restrict__ q,
    const __hip_bfloat16* __restrict__ k, const __hip_bfloat16* __restrict__ v,
    float scale)
{
  __shared__ float red[4][4][34];
  const int tid = threadIdx.x, lane = tid & 63, wv = tid >> 6;
  const int dl = lane & 7;
  const int G = wv*8 + (lane >> 3);
  const int l0 = blockIdx.x*4, h = blockIdx.y, b = blockIdx.z;

  float4 qr[4];
  #pragma unroll
  for(int j=0; j<4; j++)
    qr[j] = *(const float4*)(q + ((size_t)((l0+j)*4 + b))*256 + h*32 + dl*4);

  const unsigned short* kb = (const unsigned short*)k + ((size_t)b*HW)*256 + h*32 + dl*4;
  const unsigned short* vb = (const unsigned short*)v + ((size_t)b*HW)*256 + h*32 + dl*4;

  float m[4], ls[4]; f32x4 acc[4];
  #pragma unroll
  for(int j=0; j<4; j++){ m[j] = -1e30f; ls[j] = 0.f; acc[j] = (f32x4){0.f,0.f,0.f,0.f}; }

  for(int s=G; s<HW; s+=32){
    ushort4 k4 = *(const ushort4*)(kb + (size_t)s*256);
    ushort4 v4 = *(const ushort4*)(vb + (size_t)s*256);
    float kx = u2f(k4.x), ky = u2f(k4.y), kz = u2f(k4.z), kw = u2f(k4.w);
    float vx = u2f(v4.x), vy = u2f(v4.y), vz = u2f(v4.z), vw = u2f(v4.w);
    #pragma unroll
    for(int j=0; j<4; j++){
      float e = qr[j].x*kx + qr[j].y*ky + qr[j].z*kz + qr[j].w*kw;
      e += __shfl_xor(e, 1); e += __shfl_xor(e, 2); e += __shfl_xor(e, 4);
      e *= scale;
      float nm = fmaxf(m[j], e);
      float ff = __expf(m[j] - nm);
      float p  = __expf(e - nm);
      ls[j] = ls[j]*ff + p;
      acc[j][0] = acc[j][0]*ff + p*vx;
      acc[j][1] = acc[j][1]*ff + p*vy;
      acc[j][2] = acc[j][2]*ff + p*vz;
      acc[j][3] = acc[j][3]*ff + p*vw;
      m[j] = nm;
    }
  }
  #pragma unroll
  for(int off=8; off<64; off<<=1){
    #pragma unroll
    for(int j=0; j<4; j++){
      float om = __shfl_xor(m[j], off);
      float ol = __shfl_xor(ls[j], off);
      f32x4 oa;
      oa[0] = __shfl_xor(acc[j][0], off); oa[1] = __shfl_xor(acc[j][1], off);
      oa[2] = __shfl_xor(acc[j][2], off); oa[3] = __shfl_xor(acc[j][3], off);
      float nm = fmaxf(m[j], om);
      float fa = __expf(m[j] - nm), fb = __expf(om - nm);
      ls[j] = ls[j]*fa + ol*fb;
      #pragma unroll
      for(int t=0; t<4; t++) acc[j][t] = acc[j][t]*fa + oa[t]*fb;
      m[j] = nm;
    }
  }
  if(lane < 8){
    #pragma unroll
    for(int j=0; j<4; j++){
      if(lane == 0){ red[wv][j][0] = m[j]; red[wv][j][1] = ls[j]; }
      #pragma unroll
      for(int t=0; t<4; t++) red[wv][j][2 + dl*4 + t] = acc[j][t];
    }
  }
  __syncthreads();
  if(wv == 0 && lane < 8){
    #pragma unroll
    for(int j=0; j<4; j++){
      float M = red[0][j][0], L = red[0][j][1];
      f32x4 A;
      #pragma unroll
      for(int t=0; t<4; t++) A[t] = red[0][j][2 + dl*4 + t];
      #pragma unroll
      for(int w2=1; w2<4; w2++){
        float om = red[w2][j][0], ol = red[w2][j][1];
        float nm = fmaxf(M, om);
        float fa = __expf(M - nm), fb = __expf(om - nm);
        L = L*fa + ol*fb;
        #pragma unroll
        for(int t=0; t<4; t++) A[t] = A[t]*fa + red[w2][j][2 + dl*4 + t]*fb;
        M = nm;
      }
      float inv = 1.0f/L;
      float4 o4 = make_float4(A[0]*inv, A[1]*inv, A[2]*inv, A[3]*inv);
      *(float4*)(out + ((size_t)((l0+j)*4 + b))*256 + h*32 + dl*4) = o4;
    }
  }
}

// ---------- LayerNorm over C=256 ----------
__global__ __launch_bounds__(256) void k_ln(
    float* dst, const float* x, const float* t2, vp g, vp bb, size_t go, const int* dflag)
{
  __shared__ float red[256];
  int f = *dflag;
  int c = threadIdx.x; int tok = blockIdx.x;
  float v = x[(size_t)tok*256 + c];
  if(t2) v += t2[(size_t)tok*256 + c];
  red[c] = v; __syncthreads();
  for(int s=128; s>0; s>>=1){ if(c<s) red[c] += red[c+s]; __syncthreads(); }
  float mu = red[0]*(1.f/256.f);
  __syncthreads();
  float dv = v - mu;
  red[c] = dv*dv; __syncthreads();
  for(int s=128; s>0; s>>=1){ if(c<s) red[c] += red[c+s]; __syncthreads(); }
  float var = red[0]*(1.f/256.f);
  float r = rsqrtf(var + 1e-5f);
  dst[(size_t)tok*256 + c] = dv*r*ldf(g, go+c, f) + ldf(bb, go+c, f);
}

__global__ void k_addqe(float* dst, const float* outq, vp qe, const int* dflag){
  int f = *dflag;
  int c = threadIdx.x; int tok = blockIdx.x; int l = tok >> 2;
  dst[(size_t)tok*256 + c] = outq[(size_t)tok*256 + c] + ldf(qe, (size_t)l*256 + c, f);
}

__global__ void k_write_hs(void* out, const float* lnout, const int* dflag){
  int f = *dflag;
  int c = threadIdx.x; int tok = blockIdx.x; int l = tok >> 2; int b = tok & 3;
  float v = lnout[(size_t)tok*256 + c];
  size_t o = ((size_t)(b*100+l))*256 + c;
  if(f) ((float*)out)[o] = v;
  else  ((__hip_bfloat16*)out)[o] = __float2bfloat16(v);
}

extern "C" void kernel_launch(void* const* d_in, const int* in_sizes, int n_in,
                              void* d_out, int out_size, void* d_ws, size_t ws_size,
                              hipStream_t stream) {
  vp src       = d_in[0];
  vp query_emb = d_in[2];
  vp pos       = d_in[3];
  vp conva_w   = d_in[4];
  vp q_w = d_in[5];  vp q_b = d_in[6];
  vp k_w = d_in[7];  vp k_b = d_in[8];
  vp v_w = d_in[9];  vp v_b = d_in[10];
  vp gamma = d_in[11];
  vp convb_w = d_in[12];
  vp bneck_w = d_in[13];
  vp sa_in_w = d_in[14];  vp sa_in_b = d_in[15];
  vp sa_out_w = d_in[16]; vp sa_out_b = d_in[17];
  vp ca_in_w = d_in[18];  vp ca_in_b = d_in[19];
  vp ca_out_w = d_in[20]; vp ca_out_b = d_in[21];
  vp lin1_w = d_in[22];   vp lin1_b = d_in[23];
  vp lin2_w = d_in[24];   vp lin2_b = d_in[25];
  vp n1g = d_in[26]; vp n1b = d_in[27];
  vp n2g = d_in[28]; vp n2b = d_in[29];
  vp n3g = d_in[30]; vp n3b = d_in[31];
  vp normg = d_in[32]; vp normb = d_in[33];

  const size_t MEG = 1048576;
  float* ws   = (float*)d_ws;
  float* memf  = ws;                    // 4M floats
  float* xi    = ws + 4*MEG;            // 4M
  float* y64a  = ws + 8*MEG;            // 1M
  float* y64b  = ws + 9*MEG;            // 1M
  float* vb_   = ws + 10*MEG;           // 1M
  float* qb_   = ws + 11*MEG;           // 128K
  float* kb_   = ws + 11*MEG + 131072;  // 128K
  float* y256  = ws + 9*MEG;            // 4M (overlaps dead cc buffers)
  float* mem_t = xi;                    // decoder
  __hip_bfloat16* kproj = (__hip_bfloat16*)memf;
  __hip_bfloat16* vproj = (__hip_bfloat16*)(ws + 8*MEG);
  float* sm    = ws + 13*MEG + 262144;
  float* outq   = sm;
  float* xq     = sm + 102400;
  float* qproj  = sm + 204800;
  float* kself  = sm + 307200;
  float* vself  = sm + 409600;
  float* attout = sm + 512000;
  float* t2     = sm + 614400;
  float* ffn1   = sm + 716800;
  float* lnout  = sm + 1536000;
  unsigned short* Wp = (unsigned short*)(ws + 15532032);
  int*   dflag  = (int*)(ws + 15532032 + 589824);

  const int NFULL = 4194304;
  const float scale = 0.17677669529663687f;

  k_detect<<<1, 256, 0, stream>>>(dflag, (const unsigned short*)src);
  k_cvt<<<(NFULL+255)/256, 256, 0, stream>>>(memf, src, NFULL, dflag);

  // ------------- encoder -------------
  for(int i=0; i<6; i++){
    k_addpos<<<(NFULL+255)/256, 256, 0, stream>>>(xi, memf, pos, NFULL, dflag);
    k_repack<<<72, 256, 0, stream>>>(Wp, conva_w, (size_t)i*147456, 256, 64, dflag);
    k_conv3x3_mfma<<<dim3(64,1,4), 256, 0, stream>>>(y64a, xi, nullptr, Wp, 256, 0, 64, 1);
    for(int pass=0; pass<2; pass++){
      const float* cx = pass ? y64b : y64a;
      float* cy       = pass ? y64a : y64b;
      k_conv1x1<<<dim3(64,8,4),  64, 0, stream>>>(qb_, cx, q_w, (size_t)i*512,  q_b, (size_t)i*8,  64, 8,  dflag);
      k_conv1x1<<<dim3(64,8,4),  64, 0, stream>>>(kb_, cx, k_w, (size_t)i*512,  k_b, (size_t)i*8,  64, 8,  dflag);
      k_conv1x1<<<dim3(64,64,4), 64, 0, stream>>>(vb_, cx, v_w, (size_t)i*4096, v_b, (size_t)i*64, 64, 64, dflag);
      k_cc_fused<<<dim3(64,4), 256, 0, stream>>>(cy, vb_, qb_, kb_, cx, gamma, (size_t)i, dflag);
    }
    k_repack<<<72, 256, 0, stream>>>(Wp, convb_w, (size_t)i*147456, 64, 256, dflag);
    k_conv3x3_mfma<<<dim3(64,4,4), 256, 0, stream>>>(y256, y64a, nullptr, Wp, 64, 0, 256, 1);
    k_repack<<<576, 256, 0, stream>>>(Wp, bneck_w, (size_t)i*1179648, 512, 256, dflag);
    k_conv3x3_mfma<<<dim3(64,4,4), 256, 0, stream>>>(memf, xi, y256, Wp, 256, 256, 256, 0);
  }

  // ------------- decoder prep (before kproj overwrites memf) -------------
  k_mk_tokens<<<dim3(4096,4), 256, 0, stream>>>(mem_t, memf);
  k_write_mem<<<(NFULL+255)/256, 256, 0, stream>>>(d_out, memf, NFULL, dflag);
  k_zero<<<400, 256, 0, stream>>>(outq, 102400);

  // ------------- decoder layers -------------
  for(int i=0; i<6; i++){
    size_t iw = (size_t)i*196608, ib = (size_t)i*768;
    size_t ow = (size_t)i*65536,  ob = (size_t)i*256;
    // self-attention
    k_addqe<<<400, 256, 0, stream>>>(xq, outq, query_emb, dflag);
    k_gemm<<<dim3(4,7), 256, 0, stream>>>(qproj, xq,   sa_in_w, iw,        sa_in_b, ib,     nullptr, 400, 256, 256, 0, dflag);
    k_gemm<<<dim3(4,7), 256, 0, stream>>>(kself, xq,   sa_in_w, iw+65536,  sa_in_b, ib+256, nullptr, 400, 256, 256, 0, dflag);
    k_gemm<<<dim3(4,7), 256, 0, stream>>>(vself, outq, sa_in_w, iw+131072, sa_in_b, ib+512, nullptr, 400, 256, 256, 0, dflag);
    k_attn<<<dim3(100,8,4), 64, 0, stream>>>(attout, qproj, kself, vself,
        4, 100, (size_t)256, (size_t)1024, scale);
    k_gemm<<<dim3(4,7), 256, 0, stream>>>(t2, attout, sa_out_w, ow, sa_out_b, ob, nullptr, 400, 256, 256, 0, dflag);
    k_ln<<<400, 256, 0, stream>>>(outq, outq, t2, n1g, n1b, ob, dflag);
    // cross-attention
    k_addqe<<<400, 256, 0, stream>>>(xq, outq, query_emb, dflag);
    k_gemm<<<dim3(4,7), 256, 0, stream>>>(qproj, xq, ca_in_w, iw, ca_in_b, ib, nullptr, 400, 256, 256, 0, dflag);
    k_gemm_mfma<<<dim3(4,256), 256, 0, stream>>>(kproj, mem_t, ca_in_w, iw+65536,  ca_in_b, ib+256, pos,     16384, 256, 256, dflag);
    k_gemm_mfma<<<dim3(4,256), 256, 0, stream>>>(vproj, mem_t, ca_in_w, iw+131072, ca_in_b, ib+512, nullptr, 16384, 256, 256, dflag);
    k_attn_x<<<dim3(25,8,4), 256, 0, stream>>>(attout, qproj, kproj, vproj, scale);
    k_gemm<<<dim3(4,7), 256, 0, stream>>>(t2, attout, ca_out_w, ow, ca_out_b, ob, nullptr, 400, 256, 256, 0, dflag);
    k_ln<<<400, 256, 0, stream>>>(outq, outq, t2, n2g, n2b, ob, dflag);
    // FFN
    k_gemm<<<dim3(32,7), 256, 0, stream>>>(ffn1, outq, lin1_w, (size_t)i*524288, lin1_b, (size_t)i*2048, nullptr, 400, 2048, 256, 1, dflag);
    k_gemm<<<dim3(4,7),  256, 0, stream>>>(t2,   ffn1, lin2_w, (size_t)i*524288, lin2_b, ob,             nullptr, 400, 256, 2048, 0, dflag);
    k_ln<<<400, 256, 0, stream>>>(outq, outq, t2, n3g, n3b, ob, dflag);
  }

  k_ln<<<400, 256, 0, stream>>>(lnout, outq, nullptr, normg, normb, (size_t)0, dflag);
  k_write_hs<<<400, 256, 0, stream>>>(d_out, lnout, dflag);
}